// Round 4
// baseline (409.119 us; speedup 1.0000x reference)
//
#include <hip/hip_runtime.h>
#include <hip/hip_bf16.h>
#include <math.h>

#define N_PTS 16384
#define NLAYER 4

typedef __attribute__((ext_vector_type(8))) short bfrag;
typedef __attribute__((ext_vector_type(4))) float f32x4;
typedef __attribute__((ext_vector_type(4))) unsigned short u16x4;
typedef unsigned short ushort_t;
typedef unsigned int uint_t;

__device__ __forceinline__ ushort_t f2b(float f) {
  __hip_bfloat16 h = __float2bfloat16(f);
  return *reinterpret_cast<const ushort_t*>(&h);
}
__device__ __forceinline__ float b2f(ushort_t u) {
  union { uint_t i; float f; } c; c.i = ((uint_t)u) << 16; return c.f;
}
__device__ __forceinline__ float blo(uint_t u) {
  union { uint_t i; float f; } c; c.i = u << 16; return c.f;
}
__device__ __forceinline__ float bhi(uint_t u) {
  union { uint_t i; float f; } c; c.i = u & 0xffff0000u; return c.f;
}

// async global->LDS, 16B per lane. LDS dest must be wave-uniform base;
// HW adds lane*16.
__device__ __forceinline__ void gload16(const ushort_t* g, ushort_t* l) {
  __builtin_amdgcn_global_load_lds(
      (const __attribute__((address_space(1))) unsigned int*)g,
      (__attribute__((address_space(3))) unsigned int*)l, 16, 0, 0);
}

// ---------------------------------------------------------------------------
__global__ __launch_bounds__(256) void base_kernel(
    const float* __restrict__ enc, const float* __restrict__ W_in,
    const float* __restrict__ b_in, float* __restrict__ base)
{
  int b = blockIdx.x, j = threadIdx.x;
  __shared__ float se[256];
  se[j] = enc[b * 256 + j];
  __syncthreads();
  float acc = b_in[j] + W_in[j];
  for (int i = 1; i < 256; ++i) acc += se[i] * W_in[i * 256 + j];
  base[b * 256 + j] = acc;
}

__global__ __launch_bounds__(256) void embed_kernel(
    const float* __restrict__ base, const int* __restrict__ batch_idx,
    const float* __restrict__ pos, const float* __restrict__ W_in,
    float* __restrict__ h, ushort_t* __restrict__ h_bf)
{
  int n = blockIdx.x, j = threadIdx.x;
  int b = batch_idx[n];
  float px = pos[n * 3 + 0], py = pos[n * 3 + 1], pz = pos[n * 3 + 2];
  float v = base[b * 256 + j]
      + px * W_in[256 * 256 + j] + py * W_in[257 * 256 + j] + pz * W_in[258 * 256 + j];
  h[(size_t)n * 256 + j] = v;
  h_bf[(size_t)n * 256 + j] = f2b(v);
}

// ---------------------------------------------------------------------------
__global__ __launch_bounds__(256) void prep_qkv(
    const float* __restrict__ Wq, const float* __restrict__ Wk,
    const float* __restrict__ Wv, const float* __restrict__ We,
    ushort_t* __restrict__ out)
{
  int idx = blockIdx.x * 256 + threadIdx.x;  // < 4*640*256
  int l = idx / (640 * 256);
  int rem = idx - l * (640 * 256);
  int j = rem >> 8, k = rem & 255;
  float v = 0.f;
  if (j < 128) v = Wq[((size_t)l * 256 + k) * 128 + j];
  else if (j < 328) {
    int p = j - 128, hq = p / 50, r = p - hq * 50;
    const float* wq = &Wq[((size_t)l * 256 + k) * 128 + hq * 32];
    const float* we = &We[((size_t)l * 50 + r) * 128 + hq * 32];
#pragma unroll
    for (int d = 0; d < 32; ++d) v += wq[d] * we[d];
  } else if (j < 456) v = Wk[((size_t)l * 256 + k) * 128 + (j - 328)];
  else if (j < 584) v = Wv[((size_t)l * 256 + k) * 128 + (j - 456)];
  out[idx] = f2b(v);
}

__global__ __launch_bounds__(256) void prep_bcat(
    const float* __restrict__ We, const float* __restrict__ Wo, ushort_t* __restrict__ out)
{
  int idx = blockIdx.x * 256 + threadIdx.x;  // < 4*256*352
  if (idx >= 4 * 256 * 352) return;
  int l = idx / (256 * 352);
  int rem = idx - l * (256 * 352);
  int j = rem / 352, k2 = rem - j * 352;
  float v = 0.f;
  if (k2 < 128) v = Wo[((size_t)l * 128 + k2) * 256 + j];
  else if (k2 < 328) {
    int p = k2 - 128, hq = p / 50, r = p - hq * 50;
    const float* we = &We[((size_t)l * 50 + r) * 128 + hq * 32];
    const float* wo = &Wo[((size_t)l * 128 + hq * 32) * 256 + j];
#pragma unroll
    for (int d = 0; d < 32; ++d) v += we[d] * wo[(size_t)d * 256];
  }
  out[idx] = f2b(v);
}

__global__ __launch_bounds__(256) void prep_wfc(
    const float* __restrict__ Wfc, ushort_t* __restrict__ out)
{
  int idx = blockIdx.x * 256 + threadIdx.x;  // < 4*256*256
  int l = idx >> 16, rem = idx & 65535;
  int j = rem >> 8, k = rem & 255;
  out[idx] = f2b(Wfc[((size_t)l * 256 + k) * 256 + j]);
}

__global__ __launch_bounds__(256) void prep_wout(
    const float* __restrict__ W_out, ushort_t* __restrict__ out)
{
  int idx = blockIdx.x * 256 + threadIdx.x;  // < 128*256
  int j = idx >> 8, k = idx & 255;
  out[idx] = (j < 103) ? f2b(W_out[(size_t)k * 103 + j]) : (ushort_t)0;
}

// ---------------------------------------------------------------------------
// bf16 MFMA GEMM, m97 structure: 128x128 tile, BK=32, 4 waves (2x2),
// linear LDS [128][32], global_load_lds 16B staging.
// EPI 0: split bf16 write qext_b(328)/kvb(256), cols<584
// EPI 1: +bias, fp32 ld=103, guard c<103
// EPI 2: +bias+resid fp32 (ld 256) in-place
// EPI 3: +bias+gelu, fp32 + bf16 (ld 256)
template<int EPI>
__global__ __launch_bounds__(256) void gemm_bf16(
    const ushort_t* __restrict__ A, const ushort_t* __restrict__ BT,
    const float* __restrict__ bias, const float* __restrict__ resid,
    float* __restrict__ Cf, ushort_t* __restrict__ Cb, ushort_t* __restrict__ Cb2,
    int K)
{
  __shared__ __align__(16) ushort_t As[128 * 32];
  __shared__ __align__(16) ushort_t Bs[128 * 32];
  const int tid = threadIdx.x;
  const int m0 = blockIdx.x * 128, n0 = blockIdx.y * 128;
  const int lane = tid & 63, wv = tid >> 6;
  const int wm = wv >> 1, wn = wv & 1;
  const int l15 = lane & 15, l4 = lane >> 4;

  // staging: chunk i = set*256 + wv*64 + lane; row = i>>2, kc = (i&3)*8
  const int srow = wv * 16 + (lane >> 2);
  const int skc = (lane & 3) << 3;
  const ushort_t* gA0 = A + (size_t)(m0 + srow) * K + skc;
  const ushort_t* gA1 = gA0 + (size_t)64 * K;
  const ushort_t* gB0 = BT + (size_t)(n0 + srow) * K + skc;
  const ushort_t* gB1 = gB0 + (size_t)64 * K;
  ushort_t* lA0 = As + wv * 512;
  ushort_t* lA1 = As + 2048 + wv * 512;
  ushort_t* lB0 = Bs + wv * 512;
  ushort_t* lB1 = Bs + 2048 + wv * 512;

  f32x4 acc[4][4];
#pragma unroll
  for (int i = 0; i < 4; ++i)
#pragma unroll
    for (int j = 0; j < 4; ++j) acc[i][j] = (f32x4){0.f, 0.f, 0.f, 0.f};

  for (int k0 = 0; k0 < K; k0 += 32) {
    gload16(gA0 + k0, lA0);
    gload16(gA1 + k0, lA1);
    gload16(gB0 + k0, lB0);
    gload16(gB1 + k0, lB1);
    __syncthreads();
    bfrag af[4], bf[4];
#pragma unroll
    for (int m = 0; m < 4; ++m)
      af[m] = *(const bfrag*)(As + (wm * 64 + m * 16 + l15) * 32 + l4 * 8);
#pragma unroll
    for (int nn = 0; nn < 4; ++nn)
      bf[nn] = *(const bfrag*)(Bs + (wn * 64 + nn * 16 + l15) * 32 + l4 * 8);
#pragma unroll
    for (int m = 0; m < 4; ++m)
#pragma unroll
      for (int nn = 0; nn < 4; ++nn)
        acc[m][nn] = __builtin_amdgcn_mfma_f32_16x16x32_bf16(af[m], bf[nn], acc[m][nn], 0, 0, 0);
    __syncthreads();
  }

#pragma unroll
  for (int m = 0; m < 4; ++m) {
    const int rbase = m0 + wm * 64 + m * 16 + l4 * 4;
#pragma unroll
    for (int nn = 0; nn < 4; ++nn) {
      const int c = n0 + wn * 64 + nn * 16 + l15;
#pragma unroll
      for (int i = 0; i < 4; ++i) {
        const int r = rbase + i;
        float v = acc[m][nn][i];
        if (EPI == 0) {
          if (c < 328) Cb[(size_t)r * 328 + c] = f2b(v);
          else if (c < 584) Cb2[(size_t)r * 256 + (c - 328)] = f2b(v);
        } else if (EPI == 1) {
          if (c < 103) Cf[(size_t)r * 103 + c] = v + bias[c];
        } else if (EPI == 2) {
          Cf[(size_t)r * 256 + c] = v + bias[c] + resid[(size_t)r * 256 + c];
        } else {
          float x = v + bias[c];
          float t = tanhf(0.7978845608028654f * (x + 0.044715f * x * x * x));
          float gl = 0.5f * x * (1.f + t);
          Cf[(size_t)r * 256 + c] = gl;
          Cb[(size_t)r * 256 + c] = f2b(gl);
        }
      }
    }
  }
}

// ---------------------------------------------------------------------------
// Group-local attention, two-phase (K then V), quarter-group blocks.
// 512 blocks x 512 threads: block = (group g = bid&127, quarter q = bid>>7),
// covers points q*32..q*32+31; wave handles 4 points. XCD swizzle: all 4
// blocks of a group share bid%8.
__global__ __launch_bounds__(512) void attn_kernel(
    const ushort_t* __restrict__ qext, const ushort_t* __restrict__ kvb,
    const float* __restrict__ pos, const int* __restrict__ nbrs,
    const float* __restrict__ mask, ushort_t* __restrict__ Amsg)
{
  __shared__ ushort_t sKV[128 * 136];     // 34.8 KB (K phase, then V)
  __shared__ float    sPos[384];
  __shared__ float    sA[32][64];         // 8 KB, persists across phases
  __shared__ int      sRnAll[32][16];     // 2 KB, persists
  __shared__ ushort_t sQ[8][128];         // per-wave
  __shared__ float    sQE[8][4][52];      // per-wave, padded fp32 qWe
  __shared__ ushort_t sRbf[8][16][52];    // per-wave, bf16 rbf
  __shared__ float    sD[8][16];
  __shared__ float    sMk[8][16];

  const int tid = threadIdx.x;
  const int lane = tid & 63, w = tid >> 6;
  const int g = blockIdx.x & 127, q = blockIdx.x >> 7;
  const int base_pt = g * 128;
  const int kk = lane >> 2, hh = lane & 3;

  // stage K halves (cols 0-127) of the whole group's kvb rows
  for (int e = tid; e < 128 * 16; e += 512) {
    int r = e >> 4, c8 = e & 15;
    *(uint4*)(&sKV[r * 136 + c8 * 8]) =
        *(const uint4*)(kvb + (size_t)(base_pt + r) * 256 + c8 * 8);
  }
  for (int e = tid; e < 384; e += 512) sPos[e] = pos[(size_t)base_pt * 3 + e];
  __syncthreads();

  // ---- phase 1: logits + softmax + arbf
  for (int it = 0; it < 4; ++it) {
    const int pt = w * 4 + it;
    const int rl = q * 32 + pt;
    const int n = base_pt + rl;
    if (lane < 16) {
      int nb = nbrs[n * 16 + lane];
      int rn = nb - base_pt;
      sRnAll[pt][lane] = rn;
      sMk[w][lane] = mask[n * 16 + lane];
      float dx = sPos[rn * 3 + 0] - sPos[rl * 3 + 0];
      float dy = sPos[rn * 3 + 1] - sPos[rl * 3 + 1];
      float dz = sPos[rn * 3 + 2] - sPos[rl * 3 + 2];
      sD[w][lane] = sqrtf(dx * dx + dy * dy + dz * dz + 1e-12f);
      sRbf[w][lane][50] = 0; sRbf[w][lane][51] = 0;
    }
    if (lane < 16)
      *(uint4*)(&sQ[w][lane * 8]) = *(const uint4*)(qext + (size_t)n * 328 + lane * 8);
    if (lane < 50) {
      uint2 u = *(const uint2*)(qext + (size_t)n * 328 + 128 + lane * 4);
      int p = lane * 4;
#pragma unroll
      for (int e = 0; e < 4; ++e) {
        ushort_t bb = ((const ushort_t*)&u)[e];
        int pp = p + e, h2 = pp / 50, r = pp - h2 * 50;
        sQE[w][h2][r] = b2f(bb);
      }
    }
    if (lane < 8) sQE[w][lane >> 1][50 + (lane & 1)] = 0.f;
    // rbf -> bf16 LDS
    {
      int kk2 = lane & 15;
      float dk = sD[w][kk2];
      int r0 = lane >> 4;
#pragma unroll
      for (int j = 0; j < 13; ++j) {
        int r = r0 + j * 4;
        if (r < 50) {
          float t = (dk - (2.f / 49.f) * (float)r) * 24.5f;
          sRbf[w][kk2][r] = f2b(__expf(-0.5f * t * t));
        }
      }
    }
    // logits: lane = (kk, hh)
    int rn = sRnAll[pt][kk];
    const ushort_t* krow = &sKV[rn * 136 + hh * 32];
    float qk = 0.f;
#pragma unroll
    for (int c8 = 0; c8 < 4; ++c8) {
      uint4 kv4 = *(const uint4*)(krow + c8 * 8);
      const uint_t* q4 = (const uint_t*)(&sQ[w][hh * 32 + c8 * 8]);
      uint_t qa = q4[0], qb = q4[1], qc = q4[2], qd = q4[3];
      qk += blo(qa) * blo(kv4.x) + bhi(qa) * bhi(kv4.x)
          + blo(qb) * blo(kv4.y) + bhi(qb) * bhi(kv4.y)
          + blo(qc) * blo(kv4.z) + bhi(qc) * bhi(kv4.z)
          + blo(qd) * blo(kv4.w) + bhi(qd) * bhi(kv4.w);
    }
    float qe = 0.f;
#pragma unroll
    for (int c = 0; c < 13; ++c) {
      float4 qv = *(const float4*)(&sQE[w][hh][c * 4]);
      uint2 rv = *(const uint2*)(&sRbf[w][kk][c * 4]);
      qe += qv.x * blo(rv.x) + qv.y * bhi(rv.x)
          + qv.z * blo(rv.y) + qv.w * bhi(rv.y);
    }
    float lg = 0.17677669529663687f * (qk + qe);
    lg = (sMk[w][kk] > 0.f) ? lg : -1e9f;

    float mx = lg;
#pragma unroll
    for (int off = 4; off < 64; off <<= 1) mx = fmaxf(mx, __shfl_xor(mx, off, 64));
    float ex = __expf(lg - mx);
    float sm = ex;
#pragma unroll
    for (int off = 4; off < 64; off <<= 1) sm += __shfl_xor(sm, off, 64);
    float a = ex / sm * sMk[w][kk];
    sA[pt][kk * 4 + hh] = a;

    // arbf
    if (lane < 50) {
      float r0 = 0.f, r1 = 0.f, r2 = 0.f, r3 = 0.f;
#pragma unroll
      for (int k2 = 0; k2 < 16; ++k2) {
        float rb = b2f(sRbf[w][k2][lane]);
        r0 += sA[pt][k2 * 4 + 0] * rb;
        r1 += sA[pt][k2 * 4 + 1] * rb;
        r2 += sA[pt][k2 * 4 + 2] * rb;
        r3 += sA[pt][k2 * 4 + 3] * rb;
      }
      Amsg[(size_t)n * 352 + 128 + 0 * 50 + lane] = f2b(r0);
      Amsg[(size_t)n * 352 + 128 + 1 * 50 + lane] = f2b(r1);
      Amsg[(size_t)n * 352 + 128 + 2 * 50 + lane] = f2b(r2);
      Amsg[(size_t)n * 352 + 128 + 3 * 50 + lane] = f2b(r3);
    }
  }
  __syncthreads();

  // restage V halves (cols 128-255)
  for (int e = tid; e < 128 * 16; e += 512) {
    int r = e >> 4, c8 = e & 15;
    *(uint4*)(&sKV[r * 136 + c8 * 8]) =
        *(const uint4*)(kvb + (size_t)(base_pt + r) * 256 + 128 + c8 * 8);
  }
  __syncthreads();

  // ---- phase 2: msgv (2 d per lane)
  for (int it = 0; it < 4; ++it) {
    const int pt = w * 4 + it;
    const int n = base_pt + q * 32 + pt;
    const int h2 = lane >> 4;
    float m0 = 0.f, m1 = 0.f;
#pragma unroll
    for (int k2 = 0; k2 < 16; ++k2) {
      int rn = sRnAll[pt][k2];
      uint_t vv = *(const uint_t*)(&sKV[rn * 136 + lane * 2]);
      float a = sA[pt][k2 * 4 + h2];
      m0 += a * blo(vv);
      m1 += a * bhi(vv);
    }
    uint_t o = (uint_t)f2b(m0) | ((uint_t)f2b(m1) << 16);
    *(uint_t*)(&Amsg[(size_t)n * 352 + lane * 2]) = o;
    if (lane < 24) Amsg[(size_t)n * 352 + 328 + lane] = 0;
  }
}

// ---------------------------------------------------------------------------
__global__ __launch_bounds__(256) void ln_bf(
    const float* __restrict__ h, const float* __restrict__ g,
    const float* __restrict__ b, ushort_t* __restrict__ out)
{
  int row = blockIdx.x * 4 + (threadIdx.x >> 6);
  int lane = threadIdx.x & 63;
  float4 x = *(const float4*)(h + (size_t)row * 256 + lane * 4);
  float s = x.x + x.y + x.z + x.w;
  float ss = x.x * x.x + x.y * x.y + x.z * x.z + x.w * x.w;
#pragma unroll
  for (int off = 1; off < 64; off <<= 1) {
    s += __shfl_xor(s, off, 64);
    ss += __shfl_xor(ss, off, 64);
  }
  float mu = s * (1.f / 256.f);
  float var = ss * (1.f / 256.f) - mu * mu;
  float inv = 1.0f / sqrtf(var + 1e-5f);
  float4 gg = *(const float4*)(g + lane * 4);
  float4 bb = *(const float4*)(b + lane * 4);
  u16x4 o;
  o.x = f2b(gg.x * (x.x - mu) * inv + bb.x);
  o.y = f2b(gg.y * (x.y - mu) * inv + bb.y);
  o.z = f2b(gg.z * (x.z - mu) * inv + bb.z);
  o.w = f2b(gg.w * (x.w - mu) * inv + bb.w);
  *(u16x4*)(out + (size_t)row * 256 + lane * 4) = o;
}

// ---------------------------------------------------------------------------
extern "C" void kernel_launch(void* const* d_in, const int* in_sizes, int n_in,
                              void* d_out, int out_size, void* d_ws, size_t ws_size,
                              hipStream_t stream) {
  const float* enc    = (const float*)d_in[0];
  const float* pos    = (const float*)d_in[1];
  const int*   bidx   = (const int*)  d_in[2];
  const int*   nbrs   = (const int*)  d_in[3];
  const float* mask   = (const float*)d_in[4];
  const float* W_in   = (const float*)d_in[5];
  const float* b_in   = (const float*)d_in[6];
  const float* Wq     = (const float*)d_in[7];
  const float* Wk     = (const float*)d_in[8];
  const float* Wv     = (const float*)d_in[9];
  const float* We     = (const float*)d_in[10];
  const float* Wo     = (const float*)d_in[11];
  const float* bo     = (const float*)d_in[12];
  const float* Wfc    = (const float*)d_in[13];
  const float* bfc    = (const float*)d_in[14];
  const float* ln_g   = (const float*)d_in[15];
  const float* ln_b   = (const float*)d_in[16];
  const float* W_out  = (const float*)d_in[17];
  const float* b_out  = (const float*)d_in[18];
  float* out = (float*)d_out;

  const int N = N_PTS;
  float* ws = (float*)d_ws;
  float*    h      = ws;                                  // N*256 fp32
  ushort_t* qext_b = (ushort_t*)(h + (size_t)N * 256);    // N*328 bf16
  ushort_t* kvb    = qext_b + (size_t)N * 328;            // N*256 bf16
  ushort_t* hln    = kvb;                                 // alias, disjoint lifetime
  ushort_t* h_bf   = kvb + (size_t)N * 256;               // N*256 bf16
  ushort_t* Amsg   = h_bf + (size_t)N * 256;              // N*352 bf16
  float*    base   = (float*)(Amsg + (size_t)N * 352);    // 128*256 fp32
  ushort_t* WqkvT  = (ushort_t*)(base + 128 * 256);       // 4*640*256
  ushort_t* BcT    = WqkvT + 4 * 640 * 256;               // 4*256*352
  ushort_t* WfT    = BcT  + 4 * 256 * 352;                // 4*256*256
  ushort_t* WoT    = WfT  + 4 * 256 * 256;                // 128*256

  base_kernel<<<128, 256, 0, stream>>>(enc, W_in, b_in, base);
  embed_kernel<<<N, 256, 0, stream>>>(base, bidx, pos, W_in, h, h_bf);
  prep_qkv<<<(4 * 640 * 256) / 256, 256, 0, stream>>>(Wq, Wk, Wv, We, WqkvT);
  prep_bcat<<<(4 * 256 * 352 + 255) / 256, 256, 0, stream>>>(We, Wo, BcT);
  prep_wfc<<<(4 * 256 * 256) / 256, 256, 0, stream>>>(Wfc, WfT);
  prep_wout<<<(128 * 256) / 256, 256, 0, stream>>>(W_out, WoT);

  for (int l = 0; l < NLAYER; ++l) {
    const ushort_t* WqkvT_l = WqkvT + (size_t)l * 640 * 256;
    const ushort_t* BcT_l   = BcT   + (size_t)l * 256 * 352;
    const ushort_t* WfT_l   = WfT   + (size_t)l * 256 * 256;
    const float* bo_l  = bo  + (size_t)l * 256;
    const float* bfc_l = bfc + (size_t)l * 256;
    const float* lg_l  = ln_g + (size_t)l * 256;
    const float* lb_l  = ln_b + (size_t)l * 256;

    gemm_bf16<0><<<dim3(N / 128, 5), 256, 0, stream>>>(
        h_bf, WqkvT_l, nullptr, nullptr, nullptr, qext_b, kvb, 256);

    attn_kernel<<<512, 512, 0, stream>>>(qext_b, kvb, pos, nbrs, mask, Amsg);

    gemm_bf16<2><<<dim3(N / 128, 2), 256, 0, stream>>>(
        Amsg, BcT_l, bo_l, h, h, nullptr, nullptr, 352);

    ln_bf<<<N / 4, 256, 0, stream>>>(h, lg_l, lb_l, hln);

    gemm_bf16<3><<<dim3(N / 128, 2), 256, 0, stream>>>(
        hln, WfT_l, bfc_l, nullptr, h, h_bf, nullptr, 256);
  }

  gemm_bf16<1><<<dim3(N / 128, 1), 256, 0, stream>>>(
      h_bf, WoT, b_out, nullptr, out, nullptr, nullptr, 256);
}

// Round 5
// 374.610 us; speedup vs baseline: 1.0921x; 1.0921x over previous
//
#include <hip/hip_runtime.h>
#include <hip/hip_bf16.h>
#include <math.h>

#define N_PTS 16384
#define NLAYER 4

typedef __attribute__((ext_vector_type(8))) short bfrag;
typedef __attribute__((ext_vector_type(4))) float f32x4;
typedef __attribute__((ext_vector_type(4))) unsigned short u16x4;
typedef unsigned short ushort_t;
typedef unsigned int uint_t;

__device__ __forceinline__ ushort_t f2b(float f) {
  __hip_bfloat16 h = __float2bfloat16(f);
  return *reinterpret_cast<const ushort_t*>(&h);
}
__device__ __forceinline__ float b2f(ushort_t u) {
  union { uint_t i; float f; } c; c.i = ((uint_t)u) << 16; return c.f;
}
__device__ __forceinline__ float blo(uint_t u) {
  union { uint_t i; float f; } c; c.i = u << 16; return c.f;
}
__device__ __forceinline__ float bhi(uint_t u) {
  union { uint_t i; float f; } c; c.i = u & 0xffff0000u; return c.f;
}

// async global->LDS, 16B per lane; LDS dest wave-uniform base, HW adds lane*16.
__device__ __forceinline__ void gload16(const ushort_t* g, ushort_t* l) {
  __builtin_amdgcn_global_load_lds(
      (const __attribute__((address_space(1))) unsigned int*)g,
      (__attribute__((address_space(3))) unsigned int*)l, 16, 0, 0);
}

// ---------------------------------------------------------------------------
__global__ __launch_bounds__(256) void base_kernel(
    const float* __restrict__ enc, const float* __restrict__ W_in,
    const float* __restrict__ b_in, float* __restrict__ base)
{
  int b = blockIdx.x, j = threadIdx.x;
  __shared__ float se[256];
  se[j] = enc[b * 256 + j];
  __syncthreads();
  float acc = b_in[j] + W_in[j];
  for (int i = 1; i < 256; ++i) acc += se[i] * W_in[i * 256 + j];
  base[b * 256 + j] = acc;
}

__global__ __launch_bounds__(256) void embed_kernel(
    const float* __restrict__ base, const int* __restrict__ batch_idx,
    const float* __restrict__ pos, const float* __restrict__ W_in,
    float* __restrict__ h, ushort_t* __restrict__ h_bf)
{
  int n = blockIdx.x, j = threadIdx.x;
  int b = batch_idx[n];
  float px = pos[n * 3 + 0], py = pos[n * 3 + 1], pz = pos[n * 3 + 2];
  float v = base[b * 256 + j]
      + px * W_in[256 * 256 + j] + py * W_in[257 * 256 + j] + pz * W_in[258 * 256 + j];
  h[(size_t)n * 256 + j] = v;
  h_bf[(size_t)n * 256 + j] = f2b(v);
}

// ---------------------------------------------------------------------------
__global__ __launch_bounds__(256) void prep_qkv(
    const float* __restrict__ Wq, const float* __restrict__ Wk,
    const float* __restrict__ Wv, const float* __restrict__ We,
    ushort_t* __restrict__ out)
{
  int idx = blockIdx.x * 256 + threadIdx.x;  // < 4*640*256
  int l = idx / (640 * 256);
  int rem = idx - l * (640 * 256);
  int j = rem >> 8, k = rem & 255;
  float v = 0.f;
  if (j < 128) v = Wq[((size_t)l * 256 + k) * 128 + j];
  else if (j < 328) {
    int p = j - 128, hq = p / 50, r = p - hq * 50;
    const float* wq = &Wq[((size_t)l * 256 + k) * 128 + hq * 32];
    const float* we = &We[((size_t)l * 50 + r) * 128 + hq * 32];
#pragma unroll
    for (int d = 0; d < 32; ++d) v += wq[d] * we[d];
  } else if (j < 456) v = Wk[((size_t)l * 256 + k) * 128 + (j - 328)];
  else if (j < 584) v = Wv[((size_t)l * 256 + k) * 128 + (j - 456)];
  out[idx] = f2b(v);
}

__global__ __launch_bounds__(256) void prep_bcat(
    const float* __restrict__ We, const float* __restrict__ Wo, ushort_t* __restrict__ out)
{
  int idx = blockIdx.x * 256 + threadIdx.x;  // < 4*256*352
  if (idx >= 4 * 256 * 352) return;
  int l = idx / (256 * 352);
  int rem = idx - l * (256 * 352);
  int j = rem / 352, k2 = rem - j * 352;
  float v = 0.f;
  if (k2 < 128) v = Wo[((size_t)l * 128 + k2) * 256 + j];
  else if (k2 < 328) {
    int p = k2 - 128, hq = p / 50, r = p - hq * 50;
    const float* we = &We[((size_t)l * 50 + r) * 128 + hq * 32];
    const float* wo = &Wo[((size_t)l * 128 + hq * 32) * 256 + j];
#pragma unroll
    for (int d = 0; d < 32; ++d) v += we[d] * wo[(size_t)d * 256];
  }
  out[idx] = f2b(v);
}

__global__ __launch_bounds__(256) void prep_wfc(
    const float* __restrict__ Wfc, ushort_t* __restrict__ out)
{
  int idx = blockIdx.x * 256 + threadIdx.x;  // < 4*256*256
  int l = idx >> 16, rem = idx & 65535;
  int j = rem >> 8, k = rem & 255;
  out[idx] = f2b(Wfc[((size_t)l * 256 + k) * 256 + j]);
}

__global__ __launch_bounds__(256) void prep_wout(
    const float* __restrict__ W_out, ushort_t* __restrict__ out)
{
  int idx = blockIdx.x * 256 + threadIdx.x;  // < 128*256
  int j = idx >> 8, k = idx & 255;
  out[idx] = (j < 103) ? f2b(W_out[(size_t)k * 103 + j]) : (ushort_t)0;
}

// ---------------------------------------------------------------------------
// bf16 MFMA GEMM, 128x128 tile, BK=32, 4 waves (2x2), linear LDS,
// global_load_lds staging.
// EPI 0: split bf16 write qext_b(328)/kvb(256), cols<584
// EPI 1: +bias, fp32 ld=103, guard c<103
// EPI 3: +bias+gelu, fp32 (ld 256) + bf16 (ld 256)
template<int EPI>
__global__ __launch_bounds__(256) void gemm_bf16(
    const ushort_t* __restrict__ A, const ushort_t* __restrict__ BT,
    const float* __restrict__ bias,
    float* __restrict__ Cf, ushort_t* __restrict__ Cb, ushort_t* __restrict__ Cb2,
    int K)
{
  __shared__ __align__(16) ushort_t As[128 * 32];
  __shared__ __align__(16) ushort_t Bs[128 * 32];
  const int tid = threadIdx.x;
  const int m0 = blockIdx.x * 128, n0 = blockIdx.y * 128;
  const int lane = tid & 63, wv = tid >> 6;
  const int wm = wv >> 1, wn = wv & 1;
  const int l15 = lane & 15, l4 = lane >> 4;

  const int srow = wv * 16 + (lane >> 2);
  const int skc = (lane & 3) << 3;
  const ushort_t* gA0 = A + (size_t)(m0 + srow) * K + skc;
  const ushort_t* gA1 = gA0 + (size_t)64 * K;
  const ushort_t* gB0 = BT + (size_t)(n0 + srow) * K + skc;
  const ushort_t* gB1 = gB0 + (size_t)64 * K;
  ushort_t* lA0 = As + wv * 512;
  ushort_t* lA1 = As + 2048 + wv * 512;
  ushort_t* lB0 = Bs + wv * 512;
  ushort_t* lB1 = Bs + 2048 + wv * 512;

  f32x4 acc[4][4];
#pragma unroll
  for (int i = 0; i < 4; ++i)
#pragma unroll
    for (int j = 0; j < 4; ++j) acc[i][j] = (f32x4){0.f, 0.f, 0.f, 0.f};

  for (int k0 = 0; k0 < K; k0 += 32) {
    gload16(gA0 + k0, lA0);
    gload16(gA1 + k0, lA1);
    gload16(gB0 + k0, lB0);
    gload16(gB1 + k0, lB1);
    __syncthreads();
    bfrag af[4], bf[4];
#pragma unroll
    for (int m = 0; m < 4; ++m)
      af[m] = *(const bfrag*)(As + (wm * 64 + m * 16 + l15) * 32 + l4 * 8);
#pragma unroll
    for (int nn = 0; nn < 4; ++nn)
      bf[nn] = *(const bfrag*)(Bs + (wn * 64 + nn * 16 + l15) * 32 + l4 * 8);
#pragma unroll
    for (int m = 0; m < 4; ++m)
#pragma unroll
      for (int nn = 0; nn < 4; ++nn)
        acc[m][nn] = __builtin_amdgcn_mfma_f32_16x16x32_bf16(af[m], bf[nn], acc[m][nn], 0, 0, 0);
    __syncthreads();
  }

#pragma unroll
  for (int m = 0; m < 4; ++m) {
    const int rbase = m0 + wm * 64 + m * 16 + l4 * 4;
#pragma unroll
    for (int nn = 0; nn < 4; ++nn) {
      const int c = n0 + wn * 64 + nn * 16 + l15;
#pragma unroll
      for (int i = 0; i < 4; ++i) {
        const int r = rbase + i;
        float v = acc[m][nn][i];
        if (EPI == 0) {
          if (c < 328) Cb[(size_t)r * 328 + c] = f2b(v);
          else if (c < 584) Cb2[(size_t)r * 256 + (c - 328)] = f2b(v);
        } else if (EPI == 1) {
          if (c < 103) Cf[(size_t)r * 103 + c] = v + bias[c];
        } else {
          float x = v + bias[c];
          float t = tanhf(0.7978845608028654f * (x + 0.044715f * x * x * x));
          float gl = 0.5f * x * (1.f + t);
          Cf[(size_t)r * 256 + c] = gl;
          Cb[(size_t)r * 256 + c] = f2b(gl);
        }
      }
    }
  }
}

// ---------------------------------------------------------------------------
// Wo-GEMM + residual + LayerNorm fused. Tile 64 rows x 256 cols (full row),
// 8 waves (1x8), wave-tile 64x32, K=352. Writes hln bf16 only.
__global__ __launch_bounds__(512) void gemm_woln(
    const ushort_t* __restrict__ A, const ushort_t* __restrict__ BT,
    const float* __restrict__ bo, const float* __restrict__ resid,
    const float* __restrict__ lgm, const float* __restrict__ lbt,
    ushort_t* __restrict__ hln)
{
  __shared__ __align__(16) ushort_t As[64 * 32];
  __shared__ __align__(16) ushort_t Bs[256 * 32];
  __shared__ float pS[8][64], pSS[8][64];
  const int tid = threadIdx.x;
  const int lane = tid & 63, w = tid >> 6;
  const int l15 = lane & 15, l4 = lane >> 4;
  const int m0 = blockIdx.x * 64;
  const int K = 352;

  const int srow = lane >> 2, skc = (lane & 3) << 3;
  const ushort_t* gA = A + (size_t)(m0 + w * 16 + srow) * K + skc;    // valid for w<4
  const ushort_t* gB0 = BT + (size_t)((w * 2 + 0) * 16 + srow) * K + skc;
  const ushort_t* gB1 = BT + (size_t)((w * 2 + 1) * 16 + srow) * K + skc;
  ushort_t* lA = As + w * 512;
  ushort_t* lB0 = Bs + (w * 2 + 0) * 512;
  ushort_t* lB1 = Bs + (w * 2 + 1) * 512;

  f32x4 acc[4][2];
#pragma unroll
  for (int i = 0; i < 4; ++i) {
    acc[i][0] = (f32x4){0.f, 0.f, 0.f, 0.f};
    acc[i][1] = (f32x4){0.f, 0.f, 0.f, 0.f};
  }

  for (int k0 = 0; k0 < K; k0 += 32) {
    if (w < 4) gload16(gA + k0, lA);
    gload16(gB0 + k0, lB0);
    gload16(gB1 + k0, lB1);
    __syncthreads();
    bfrag af[4], bf[2];
#pragma unroll
    for (int m = 0; m < 4; ++m)
      af[m] = *(const bfrag*)(As + (m * 16 + l15) * 32 + l4 * 8);
#pragma unroll
    for (int nn = 0; nn < 2; ++nn)
      bf[nn] = *(const bfrag*)(Bs + (w * 32 + nn * 16 + l15) * 32 + l4 * 8);
#pragma unroll
    for (int m = 0; m < 4; ++m)
#pragma unroll
      for (int nn = 0; nn < 2; ++nn)
        acc[m][nn] = __builtin_amdgcn_mfma_f32_16x16x32_bf16(af[m], bf[nn], acc[m][nn], 0, 0, 0);
    __syncthreads();
  }

  const int c0 = w * 32 + l15;
  const int c1 = c0 + 16;
  const float bo0 = bo[c0], bo1 = bo[c1];
  const float g0 = lgm[c0], g1 = lgm[c1];
  const float b0 = lbt[c0], b1 = lbt[c1];

#pragma unroll
  for (int m = 0; m < 4; ++m) {
#pragma unroll
    for (int i = 0; i < 4; ++i) {
      const int rl = m * 16 + l4 * 4 + i;
      const size_t r = (size_t)(m0 + rl);
      float x0 = acc[m][0][i] + bo0 + resid[r * 256 + c0];
      float x1 = acc[m][1][i] + bo1 + resid[r * 256 + c1];
      acc[m][0][i] = x0; acc[m][1][i] = x1;
      float s = x0 + x1, ss = x0 * x0 + x1 * x1;
      s += __shfl_xor(s, 1, 64); ss += __shfl_xor(ss, 1, 64);
      s += __shfl_xor(s, 2, 64); ss += __shfl_xor(ss, 2, 64);
      s += __shfl_xor(s, 4, 64); ss += __shfl_xor(ss, 4, 64);
      s += __shfl_xor(s, 8, 64); ss += __shfl_xor(ss, 8, 64);
      if (l15 == 0) { pS[w][rl] = s; pSS[w][rl] = ss; }
    }
  }
  __syncthreads();
#pragma unroll
  for (int m = 0; m < 4; ++m) {
#pragma unroll
    for (int i = 0; i < 4; ++i) {
      const int rl = m * 16 + l4 * 4 + i;
      float s = 0.f, ss = 0.f;
#pragma unroll
      for (int w2 = 0; w2 < 8; ++w2) { s += pS[w2][rl]; ss += pSS[w2][rl]; }
      float mu = s * (1.f / 256.f);
      float var = ss * (1.f / 256.f) - mu * mu;
      float inv = 1.0f / sqrtf(var + 1e-5f);
      const size_t r = (size_t)(m0 + rl);
      hln[r * 256 + c0] = f2b(g0 * (acc[m][0][i] - mu) * inv + b0);
      hln[r * 256 + c1] = f2b(g1 * (acc[m][1][i] - mu) * inv + b1);
    }
  }
}

// ---------------------------------------------------------------------------
// Attention: no K/V staging (L2/L3-served), no block barriers, all LDS
// per-wave. 1024 blocks x 256 threads; wave handles 4 points.
// Grid map: g = bid&127 (group), q4 = bid>>7 -> 16-point slice.
__global__ __launch_bounds__(256) void attn_kernel(
    const ushort_t* __restrict__ qext, const ushort_t* __restrict__ kvb,
    const float* __restrict__ pos, const int* __restrict__ nbrs,
    const float* __restrict__ mask, ushort_t* __restrict__ Amsg)
{
  __shared__ __align__(16) ushort_t sQ[4][128];
  __shared__ __align__(16) float    sQE[4][4][52];
  __shared__ __align__(16) ushort_t sRbf[4][16][52];
  __shared__ float sA[4][64];
  __shared__ float sD[4][16];
  __shared__ float sMk[4][16];
  __shared__ int   sNb[4][16];

  const int tid = threadIdx.x;
  const int lane = tid & 63, w = tid >> 6;
  const int g = blockIdx.x & 127, q4 = blockIdx.x >> 7;
  const int kk = lane >> 2, hh = lane & 3;

  for (int it = 0; it < 4; ++it) {
    const int n = g * 128 + q4 * 16 + w * 4 + it;
    if (lane < 16) {
      int nb = nbrs[n * 16 + lane];
      sNb[w][lane] = nb;
      sMk[w][lane] = mask[n * 16 + lane];
      float dx = pos[nb * 3 + 0] - pos[n * 3 + 0];
      float dy = pos[nb * 3 + 1] - pos[n * 3 + 1];
      float dz = pos[nb * 3 + 2] - pos[n * 3 + 2];
      sD[w][lane] = sqrtf(dx * dx + dy * dy + dz * dz + 1e-12f);
      sRbf[w][lane][50] = 0; sRbf[w][lane][51] = 0;
      *(uint4*)(&sQ[w][lane * 8]) = *(const uint4*)(qext + (size_t)n * 328 + lane * 8);
    }
    if (lane < 50) {
      uint2 u = *(const uint2*)(qext + (size_t)n * 328 + 128 + lane * 4);
      int p = lane * 4;
#pragma unroll
      for (int e = 0; e < 4; ++e) {
        ushort_t bb = ((const ushort_t*)&u)[e];
        int pp = p + e, h2 = pp / 50, r = pp - h2 * 50;
        sQE[w][h2][r] = b2f(bb);
      }
    }
    if (lane < 8) sQE[w][lane >> 1][50 + (lane & 1)] = 0.f;
    // rbf (bf16 in LDS)
    {
      int kk2 = lane & 15;
      float dk = sD[w][kk2];
      int r0 = lane >> 4;
#pragma unroll
      for (int j = 0; j < 13; ++j) {
        int r = r0 + j * 4;
        if (r < 50) {
          float t = (dk - (2.f / 49.f) * (float)r) * 24.5f;
          sRbf[w][kk2][r] = f2b(__expf(-0.5f * t * t));
        }
      }
    }
    // logits: lane = (kk, hh); K rows straight from global (L2/L3)
    const int nb = sNb[w][kk];
    const ushort_t* krow = kvb + (size_t)nb * 256 + hh * 32;
    float qk = 0.f;
#pragma unroll
    for (int c8 = 0; c8 < 4; ++c8) {
      uint4 kv4 = *(const uint4*)(krow + c8 * 8);
      const uint_t* q4p = (const uint_t*)(&sQ[w][hh * 32 + c8 * 8]);
      uint_t qa = q4p[0], qb = q4p[1], qc = q4p[2], qd = q4p[3];
      qk += blo(qa) * blo(kv4.x) + bhi(qa) * bhi(kv4.x)
          + blo(qb) * blo(kv4.y) + bhi(qb) * bhi(kv4.y)
          + blo(qc) * blo(kv4.z) + bhi(qc) * bhi(kv4.z)
          + blo(qd) * blo(kv4.w) + bhi(qd) * bhi(kv4.w);
    }
    float qe = 0.f;
#pragma unroll
    for (int c = 0; c < 13; ++c) {
      float4 qv = *(const float4*)(&sQE[w][hh][c * 4]);
      uint2 rv = *(const uint2*)(&sRbf[w][kk][c * 4]);
      qe += qv.x * blo(rv.x) + qv.y * bhi(rv.x)
          + qv.z * blo(rv.y) + qv.w * bhi(rv.y);
    }
    float lg = 0.17677669529663687f * (qk + qe);
    lg = (sMk[w][kk] > 0.f) ? lg : -1e9f;

    float mx = lg;
#pragma unroll
    for (int off = 4; off < 64; off <<= 1) mx = fmaxf(mx, __shfl_xor(mx, off, 64));
    float ex = __expf(lg - mx);
    float sm = ex;
#pragma unroll
    for (int off = 4; off < 64; off <<= 1) sm += __shfl_xor(sm, off, 64);
    sA[w][kk * 4 + hh] = ex / sm * sMk[w][kk];

    // arbf
    if (lane < 50) {
      float r0 = 0.f, r1 = 0.f, r2 = 0.f, r3 = 0.f;
#pragma unroll
      for (int k2 = 0; k2 < 16; ++k2) {
        float rb = b2f(sRbf[w][k2][lane]);
        r0 += sA[w][k2 * 4 + 0] * rb;
        r1 += sA[w][k2 * 4 + 1] * rb;
        r2 += sA[w][k2 * 4 + 2] * rb;
        r3 += sA[w][k2 * 4 + 3] * rb;
      }
      Amsg[(size_t)n * 352 + 128 + 0 * 50 + lane] = f2b(r0);
      Amsg[(size_t)n * 352 + 128 + 1 * 50 + lane] = f2b(r1);
      Amsg[(size_t)n * 352 + 128 + 2 * 50 + lane] = f2b(r2);
      Amsg[(size_t)n * 352 + 128 + 3 * 50 + lane] = f2b(r3);
    }
    // msgv: 2 d per lane, V rows straight from global (coalesced per row)
    {
      const int h2 = lane >> 4;
      float m0v = 0.f, m1v = 0.f;
#pragma unroll
      for (int k2 = 0; k2 < 16; ++k2) {
        int nb2 = sNb[w][k2];
        uint_t vv = *(const uint_t*)(kvb + (size_t)nb2 * 256 + 128 + lane * 2);
        float a = sA[w][k2 * 4 + h2];
        m0v += a * blo(vv);
        m1v += a * bhi(vv);
      }
      uint_t o = (uint_t)f2b(m0v) | ((uint_t)f2b(m1v) << 16);
      *(uint_t*)(&Amsg[(size_t)n * 352 + lane * 2]) = o;
    }
    if (lane < 24) Amsg[(size_t)n * 352 + 328 + lane] = 0;
  }
}

// ---------------------------------------------------------------------------
extern "C" void kernel_launch(void* const* d_in, const int* in_sizes, int n_in,
                              void* d_out, int out_size, void* d_ws, size_t ws_size,
                              hipStream_t stream) {
  const float* enc    = (const float*)d_in[0];
  const float* pos    = (const float*)d_in[1];
  const int*   bidx   = (const int*)  d_in[2];
  const int*   nbrs   = (const int*)  d_in[3];
  const float* mask   = (const float*)d_in[4];
  const float* W_in   = (const float*)d_in[5];
  const float* b_in   = (const float*)d_in[6];
  const float* Wq     = (const float*)d_in[7];
  const float* Wk     = (const float*)d_in[8];
  const float* Wv     = (const float*)d_in[9];
  const float* We     = (const float*)d_in[10];
  const float* Wo     = (const float*)d_in[11];
  const float* bo     = (const float*)d_in[12];
  const float* Wfc    = (const float*)d_in[13];
  const float* bfc    = (const float*)d_in[14];
  const float* ln_g   = (const float*)d_in[15];
  const float* ln_b   = (const float*)d_in[16];
  const float* W_out  = (const float*)d_in[17];
  const float* b_out  = (const float*)d_in[18];
  float* out = (float*)d_out;

  const int N = N_PTS;
  float* ws = (float*)d_ws;
  float*    h      = ws;                                  // N*256 fp32
  ushort_t* qext_b = (ushort_t*)(h + (size_t)N * 256);    // N*328 bf16
  ushort_t* kvb    = qext_b + (size_t)N * 328;            // N*256 bf16
  ushort_t* hln    = kvb;                                 // alias, disjoint lifetime
  ushort_t* h_bf   = kvb + (size_t)N * 256;               // N*256 bf16
  ushort_t* Amsg   = h_bf + (size_t)N * 256;              // N*352 bf16
  float*    base   = (float*)(Amsg + (size_t)N * 352);    // 128*256 fp32
  ushort_t* WqkvT  = (ushort_t*)(base + 128 * 256);       // 4*640*256
  ushort_t* BcT    = WqkvT + 4 * 640 * 256;               // 4*256*352
  ushort_t* WfT    = BcT  + 4 * 256 * 352;                // 4*256*256
  ushort_t* WoT    = WfT  + 4 * 256 * 256;                // 128*256

  base_kernel<<<128, 256, 0, stream>>>(enc, W_in, b_in, base);
  embed_kernel<<<N, 256, 0, stream>>>(base, bidx, pos, W_in, h, h_bf);
  prep_qkv<<<(4 * 640 * 256) / 256, 256, 0, stream>>>(Wq, Wk, Wv, We, WqkvT);
  prep_bcat<<<(4 * 256 * 352 + 255) / 256, 256, 0, stream>>>(We, Wo, BcT);
  prep_wfc<<<(4 * 256 * 256) / 256, 256, 0, stream>>>(Wfc, WfT);
  prep_wout<<<(128 * 256) / 256, 256, 0, stream>>>(W_out, WoT);

  for (int l = 0; l < NLAYER; ++l) {
    const ushort_t* WqkvT_l = WqkvT + (size_t)l * 640 * 256;
    const ushort_t* BcT_l   = BcT   + (size_t)l * 256 * 352;
    const ushort_t* WfT_l   = WfT   + (size_t)l * 256 * 256;
    const float* bo_l  = bo  + (size_t)l * 256;
    const float* bfc_l = bfc + (size_t)l * 256;
    const float* lg_l  = ln_g + (size_t)l * 256;
    const float* lb_l  = ln_b + (size_t)l * 256;

    // [qext | k | v] = h_bf @ Wqkv
    gemm_bf16<0><<<dim3(N / 128, 5), 256, 0, stream>>>(
        h_bf, WqkvT_l, nullptr, nullptr, qext_b, kvb, 256);

    attn_kernel<<<1024, 256, 0, stream>>>(qext_b, kvb, pos, nbrs, mask, Amsg);

    // hln = LN(h + [msgv|arbf] @ Bcat + bo)  (fused, writes bf16 only)
    gemm_woln<<<N / 64, 512, 0, stream>>>(
        Amsg, BcT_l, bo_l, h, lg_l, lb_l, hln);

    // h = gelu(hln @ Wfc + bfc), fp32 + bf16
    gemm_bf16<3><<<dim3(N / 128, 2), 256, 0, stream>>>(
        hln, WfT_l, bfc_l, h, h_bf, nullptr, 256);
  }

  gemm_bf16<1><<<dim3(N / 128, 1), 256, 0, stream>>>(
      h_bf, WoT, b_out, out, nullptr, nullptr, 256);
}

// Round 6
// 359.730 us; speedup vs baseline: 1.1373x; 1.0414x over previous
//
#include <hip/hip_runtime.h>
#include <hip/hip_bf16.h>
#include <math.h>

#define N_PTS 16384
#define NLAYER 4

typedef __attribute__((ext_vector_type(8))) short bfrag;
typedef __attribute__((ext_vector_type(4))) float f32x4;
typedef __attribute__((ext_vector_type(4))) unsigned short u16x4;
typedef unsigned short ushort_t;
typedef unsigned int uint_t;

__device__ __forceinline__ ushort_t f2b(float f) {
  __hip_bfloat16 h = __float2bfloat16(f);
  return *reinterpret_cast<const ushort_t*>(&h);
}
__device__ __forceinline__ float b2f(ushort_t u) {
  union { uint_t i; float f; } c; c.i = ((uint_t)u) << 16; return c.f;
}
__device__ __forceinline__ float blo(uint_t u) {
  union { uint_t i; float f; } c; c.i = u << 16; return c.f;
}
__device__ __forceinline__ float bhi(uint_t u) {
  union { uint_t i; float f; } c; c.i = u & 0xffff0000u; return c.f;
}

// async global->LDS, 16B/lane; LDS dest wave-uniform base, HW adds lane*16.
__device__ __forceinline__ void gload16(const ushort_t* g, ushort_t* l) {
  __builtin_amdgcn_global_load_lds(
      (const __attribute__((address_space(1))) unsigned int*)g,
      (__attribute__((address_space(3))) unsigned int*)l, 16, 0, 0);
}

// ---------------------------------------------------------------------------
__global__ __launch_bounds__(256) void base_kernel(
    const float* __restrict__ enc, const float* __restrict__ W_in,
    const float* __restrict__ b_in, float* __restrict__ base)
{
  int b = blockIdx.x, j = threadIdx.x;
  __shared__ float se[256];
  se[j] = enc[b * 256 + j];
  __syncthreads();
  float acc = b_in[j] + W_in[j];
  for (int i = 1; i < 256; ++i) acc += se[i] * W_in[i * 256 + j];
  base[b * 256 + j] = acc;
}

__global__ __launch_bounds__(256) void embed_kernel(
    const float* __restrict__ base, const int* __restrict__ batch_idx,
    const float* __restrict__ pos, const float* __restrict__ W_in,
    float* __restrict__ h, ushort_t* __restrict__ h_bf)
{
  int n = blockIdx.x, j = threadIdx.x;
  int b = batch_idx[n];
  float px = pos[n * 3 + 0], py = pos[n * 3 + 1], pz = pos[n * 3 + 2];
  float v = base[b * 256 + j]
      + px * W_in[256 * 256 + j] + py * W_in[257 * 256 + j] + pz * W_in[258 * 256 + j];
  h[(size_t)n * 256 + j] = v;
  h_bf[(size_t)n * 256 + j] = f2b(v);
}

// ---------------------------------------------------------------------------
// WqkvT[l][j][k], j<128: Wq; 128..327: Wq@We^T; 328..455: Wk; 456..583: Wv; pad 0
__global__ __launch_bounds__(256) void prep_qkv(
    const float* __restrict__ Wq, const float* __restrict__ Wk,
    const float* __restrict__ Wv, const float* __restrict__ We,
    ushort_t* __restrict__ out)
{
  int idx = blockIdx.x * 256 + threadIdx.x;  // < 4*640*256
  int l = idx / (640 * 256);
  int rem = idx - l * (640 * 256);
  int j = rem >> 8, k = rem & 255;
  float v = 0.f;
  if (j < 128) v = Wq[((size_t)l * 256 + k) * 128 + j];
  else if (j < 328) {
    int p = j - 128, hq = p / 50, r = p - hq * 50;
    const float* wq = &Wq[((size_t)l * 256 + k) * 128 + hq * 32];
    const float* we = &We[((size_t)l * 50 + r) * 128 + hq * 32];
#pragma unroll
    for (int d = 0; d < 32; ++d) v += wq[d] * we[d];
  } else if (j < 456) v = Wk[((size_t)l * 256 + k) * 128 + (j - 328)];
  else if (j < 584) v = Wv[((size_t)l * 256 + k) * 128 + (j - 456)];
  out[idx] = f2b(v);
}

// BcT[l][j][k2], ld 384: k2<128: Wo[k2][j]; 128..327: (We@Wo); else 0
__global__ __launch_bounds__(256) void prep_bcat(
    const float* __restrict__ We, const float* __restrict__ Wo, ushort_t* __restrict__ out)
{
  int idx = blockIdx.x * 256 + threadIdx.x;  // < 4*256*384
  int l = idx / (256 * 384);
  int rem = idx - l * (256 * 384);
  int j = rem / 384, k2 = rem - j * 384;
  float v = 0.f;
  if (k2 < 128) v = Wo[((size_t)l * 128 + k2) * 256 + j];
  else if (k2 < 328) {
    int p = k2 - 128, hq = p / 50, r = p - hq * 50;
    const float* we = &We[((size_t)l * 50 + r) * 128 + hq * 32];
    const float* wo = &Wo[((size_t)l * 128 + hq * 32) * 256 + j];
#pragma unroll
    for (int d = 0; d < 32; ++d) v += we[d] * wo[(size_t)d * 256];
  }
  out[idx] = f2b(v);
}

__global__ __launch_bounds__(256) void prep_wfc(
    const float* __restrict__ Wfc, ushort_t* __restrict__ out)
{
  int idx = blockIdx.x * 256 + threadIdx.x;  // < 4*256*256
  int l = idx >> 16, rem = idx & 65535;
  int j = rem >> 8, k = rem & 255;
  out[idx] = f2b(Wfc[((size_t)l * 256 + k) * 256 + j]);
}

__global__ __launch_bounds__(256) void prep_wout(
    const float* __restrict__ W_out, ushort_t* __restrict__ out)
{
  int idx = blockIdx.x * 256 + threadIdx.x;  // < 128*256
  int j = idx >> 8, k = idx & 255;
  out[idx] = (j < 103) ? f2b(W_out[(size_t)k * 103 + j]) : (ushort_t)0;
}

// ---------------------------------------------------------------------------
// Fused layer tail: hln = LN(h + Amsg@Bcat + bo); g = gelu(hln@Wfc + bfc);
// h = g (fp32); [qext|kv] = g@Wqkv  (or out = g@W_out + b_out).
// MODE 0: full layer -> qkv. MODE 1: full layer -> out. MODE 2: qkv only (A0=h_bf).
// 256 blocks x 512 threads (8 waves), 64 rows/block, wave = 32-col strip.
template<int MODE>
__global__ __launch_bounds__(512, 2) void fused_layer(
    const ushort_t* __restrict__ A0,    // MODE2: h_bf (ld 256); else Amsg (ld 352)
    const ushort_t* __restrict__ BcT,   // [256][384]
    const float* __restrict__ bo,
    float* __restrict__ h,              // fp32 residual in / gelu out
    const float* __restrict__ lg, const float* __restrict__ lb,
    const ushort_t* __restrict__ WfT,   // [256][256]
    const float* __restrict__ bfc,
    const ushort_t* __restrict__ W3T,   // [640][256] (qkv) or [128][256] (out)
    const float* __restrict__ b3,       // b_out (MODE 1)
    ushort_t* __restrict__ qext_b, ushort_t* __restrict__ kvb,
    float* __restrict__ outF)
{
  __shared__ __align__(16) ushort_t R0[64 * 392];             // sA, later sHg
  __shared__ __align__(16) ushort_t R12[64 * 264 + 256 * 64]; // sH + sB; later B3
  __shared__ float pS[8][64], pSS[8][64];
  ushort_t* sA  = R0;              // [64][392] padded Amsg
  ushort_t* sHg = R0;              // [64][264] gelu out (overlays sA)
  ushort_t* sH  = R12;             // [64][264] hln
  ushort_t* sB  = R12 + 64 * 264;  // [256][64] streamed B-tile (swizzled)
  ushort_t* B3  = R12;             // [128][256] GEMM3 B panel (swizzled)

  const int tid = threadIdx.x;
  const int lane = tid & 63, w = tid >> 6;
  const int l15 = lane & 15, l4 = lane >> 4;
  const int m0 = blockIdx.x * 64;
  const int swzk = (l15 & 7) << 3;

  f32x4 acc[4][2];

  if constexpr (MODE != 2) {
    // ---- stage Amsg tile -> sA [64][392], zero K-pad 352..383
    for (int i = tid; i < 64 * 48; i += 512) {
      int r = i / 48, cc = (i - r * 48) * 8;
      uint4 v = (uint4){0, 0, 0, 0};
      if (cc < 352) v = *(const uint4*)(A0 + (size_t)(m0 + r) * 352 + cc);
      *(uint4*)(&sA[r * 392 + cc]) = v;
    }

    // ---- GEMM1: acc = Amsg @ BcT^T  (K=384, 6 stages of 64)
#pragma unroll
    for (int m = 0; m < 4; ++m) {
      acc[m][0] = (f32x4){0.f, 0.f, 0.f, 0.f};
      acc[m][1] = (f32x4){0.f, 0.f, 0.f, 0.f};
    }
    for (int ks = 0; ks < 6; ++ks) {
      const int k0 = ks * 64;
#pragma unroll
      for (int it = 0; it < 4; ++it) {
        int chunk = it * 512 + tid;
        int row = chunk >> 3;
        int kc = ((chunk & 7) << 3) ^ ((row & 7) << 3);
        gload16(BcT + (size_t)row * 384 + k0 + kc, sB + (size_t)(it * 512 + w * 64) * 8);
      }
      __syncthreads();
#pragma unroll
      for (int kk = 0; kk < 64; kk += 32) {
        bfrag af[4], bf[2];
#pragma unroll
        for (int m = 0; m < 4; ++m)
          af[m] = *(const bfrag*)(sA + (m * 16 + l15) * 392 + k0 + kk + l4 * 8);
#pragma unroll
        for (int nn = 0; nn < 2; ++nn) {
          int row = w * 32 + nn * 16 + l15;
          bf[nn] = *(const bfrag*)(sB + row * 64 + ((kk + l4 * 8) ^ swzk));
        }
#pragma unroll
        for (int m = 0; m < 4; ++m)
#pragma unroll
          for (int nn = 0; nn < 2; ++nn)
            acc[m][nn] = __builtin_amdgcn_mfma_f32_16x16x32_bf16(af[m], bf[nn], acc[m][nn], 0, 0, 0);
      }
      __syncthreads();
    }

    // ---- epilogue 1: + bo + resid(h), rowwise LN -> sH bf16
    {
      const int c0 = w * 32 + l15, c1 = c0 + 16;
      const float bo0 = bo[c0], bo1 = bo[c1];
#pragma unroll
      for (int m = 0; m < 4; ++m)
#pragma unroll
        for (int i = 0; i < 4; ++i) {
          const int rl = m * 16 + l4 * 4 + i;
          const size_t r = (size_t)(m0 + rl);
          float x0 = acc[m][0][i] + bo0 + h[r * 256 + c0];
          float x1 = acc[m][1][i] + bo1 + h[r * 256 + c1];
          acc[m][0][i] = x0; acc[m][1][i] = x1;
          float s = x0 + x1, ss = x0 * x0 + x1 * x1;
          s += __shfl_xor(s, 1, 64); ss += __shfl_xor(ss, 1, 64);
          s += __shfl_xor(s, 2, 64); ss += __shfl_xor(ss, 2, 64);
          s += __shfl_xor(s, 4, 64); ss += __shfl_xor(ss, 4, 64);
          s += __shfl_xor(s, 8, 64); ss += __shfl_xor(ss, 8, 64);
          if (l15 == 0) { pS[w][rl] = s; pSS[w][rl] = ss; }
        }
      __syncthreads();
      const float g0 = lg[c0], g1 = lg[c1];
      const float b0 = lb[c0], b1 = lb[c1];
#pragma unroll
      for (int m = 0; m < 4; ++m)
#pragma unroll
        for (int i = 0; i < 4; ++i) {
          const int rl = m * 16 + l4 * 4 + i;
          float s = 0.f, ss = 0.f;
#pragma unroll
          for (int w2 = 0; w2 < 8; ++w2) { s += pS[w2][rl]; ss += pSS[w2][rl]; }
          float mu = s * (1.f / 256.f);
          float var = ss * (1.f / 256.f) - mu * mu;
          float inv = 1.0f / sqrtf(var + 1e-5f);
          sH[rl * 264 + c0] = f2b(g0 * (acc[m][0][i] - mu) * inv + b0);
          sH[rl * 264 + c1] = f2b(g1 * (acc[m][1][i] - mu) * inv + b1);
        }
    }

    // ---- GEMM2: acc = hln @ WfT^T (K=256, 4 stages of 64)
#pragma unroll
    for (int m = 0; m < 4; ++m) {
      acc[m][0] = (f32x4){0.f, 0.f, 0.f, 0.f};
      acc[m][1] = (f32x4){0.f, 0.f, 0.f, 0.f};
    }
    for (int ks = 0; ks < 4; ++ks) {
      const int k0 = ks * 64;
#pragma unroll
      for (int it = 0; it < 4; ++it) {
        int chunk = it * 512 + tid;
        int row = chunk >> 3;
        int kc = ((chunk & 7) << 3) ^ ((row & 7) << 3);
        gload16(WfT + (size_t)row * 256 + k0 + kc, sB + (size_t)(it * 512 + w * 64) * 8);
      }
      __syncthreads();
#pragma unroll
      for (int kk = 0; kk < 64; kk += 32) {
        bfrag af[4], bf[2];
#pragma unroll
        for (int m = 0; m < 4; ++m)
          af[m] = *(const bfrag*)(sH + (m * 16 + l15) * 264 + k0 + kk + l4 * 8);
#pragma unroll
        for (int nn = 0; nn < 2; ++nn) {
          int row = w * 32 + nn * 16 + l15;
          bf[nn] = *(const bfrag*)(sB + row * 64 + ((kk + l4 * 8) ^ swzk));
        }
#pragma unroll
        for (int m = 0; m < 4; ++m)
#pragma unroll
          for (int nn = 0; nn < 2; ++nn)
            acc[m][nn] = __builtin_amdgcn_mfma_f32_16x16x32_bf16(af[m], bf[nn], acc[m][nn], 0, 0, 0);
      }
      __syncthreads();
    }

    // ---- epilogue 2: gelu -> h fp32 (next-layer residual) + sHg bf16
    {
      const int c0 = w * 32 + l15, c1 = c0 + 16;
      const float bf0 = bfc[c0], bf1 = bfc[c1];
#pragma unroll
      for (int m = 0; m < 4; ++m)
#pragma unroll
        for (int i = 0; i < 4; ++i) {
          const int rl = m * 16 + l4 * 4 + i;
          const size_t r = (size_t)(m0 + rl);
          float x0 = acc[m][0][i] + bf0;
          float x1 = acc[m][1][i] + bf1;
          float t0 = tanhf(0.7978845608028654f * (x0 + 0.044715f * x0 * x0 * x0));
          float t1 = tanhf(0.7978845608028654f * (x1 + 0.044715f * x1 * x1 * x1));
          float gl0 = 0.5f * x0 * (1.f + t0);
          float gl1 = 0.5f * x1 * (1.f + t1);
          h[r * 256 + c0] = gl0;
          h[r * 256 + c1] = gl1;
          sHg[rl * 264 + c0] = f2b(gl0);
          sHg[rl * 264 + c1] = f2b(gl1);
        }
    }
    __syncthreads();
  } else {
    // MODE 2: stage h_bf tile directly into sHg
    for (int i = tid; i < 64 * 32; i += 512) {
      int r = i >> 5, cc = (i & 31) << 3;
      *(uint4*)(&sHg[r * 264 + cc]) = *(const uint4*)(A0 + (size_t)(m0 + r) * 256 + cc);
    }
    __syncthreads();
  }

  // ---- GEMM3: [qext|kv] = g @ W3T^T  (or out). 128-col panels, K=256 resident.
  const int NB = (MODE == 1) ? 1 : 5;
  for (int nb = 0; nb < NB; ++nb) {
    if (nb) __syncthreads();
#pragma unroll
    for (int it = 0; it < 8; ++it) {
      int chunk = it * 512 + tid;
      int row = chunk >> 5;
      int kc = ((chunk & 31) << 3) ^ ((row & 7) << 3);
      gload16(W3T + (size_t)(nb * 128 + row) * 256 + kc, B3 + (size_t)(it * 512 + w * 64) * 8);
    }
    __syncthreads();
    f32x4 a3[4];
#pragma unroll
    for (int m = 0; m < 4; ++m) a3[m] = (f32x4){0.f, 0.f, 0.f, 0.f};
#pragma unroll
    for (int k0 = 0; k0 < 256; k0 += 32) {
      bfrag af[4], bf;
#pragma unroll
      for (int m = 0; m < 4; ++m)
        af[m] = *(const bfrag*)(sHg + (m * 16 + l15) * 264 + k0 + l4 * 8);
      {
        int row = w * 16 + l15;
        bf = *(const bfrag*)(B3 + row * 256 + ((k0 + l4 * 8) ^ swzk));
      }
#pragma unroll
      for (int m = 0; m < 4; ++m)
        a3[m] = __builtin_amdgcn_mfma_f32_16x16x32_bf16(af[m], bf, a3[m], 0, 0, 0);
    }
    const int c = nb * 128 + w * 16 + l15;
#pragma unroll
    for (int m = 0; m < 4; ++m)
#pragma unroll
      for (int i = 0; i < 4; ++i) {
        const size_t r = (size_t)(m0 + m * 16 + l4 * 4 + i);
        float v = a3[m][i];
        if constexpr (MODE == 1) {
          if (c < 103) outF[r * 103 + c] = v + b3[c];
        } else {
          if (c < 328) qext_b[r * 352 + c] = f2b(v);
          else if (c < 584) kvb[r * 256 + (c - 328)] = f2b(v);
        }
      }
  }
}

// ---------------------------------------------------------------------------
// Attention: K/V straight from L2/L3, all LDS per-wave, no block barriers.
// 1024 blocks x 256 threads; wave handles 4 points.
__global__ __launch_bounds__(256) void attn_kernel(
    const ushort_t* __restrict__ qext, const ushort_t* __restrict__ kvb,
    const float* __restrict__ pos, const int* __restrict__ nbrs,
    const float* __restrict__ mask, ushort_t* __restrict__ Amsg)
{
  __shared__ __align__(16) ushort_t sQ[4][128];
  __shared__ __align__(16) float    sQE[4][4][52];
  __shared__ __align__(16) ushort_t sRbf[4][16][52];
  __shared__ float sA[4][64];
  __shared__ float sD[4][16];
  __shared__ float sMk[4][16];
  __shared__ int   sNb[4][16];

  const int tid = threadIdx.x;
  const int lane = tid & 63, w = tid >> 6;
  const int g = blockIdx.x & 127, q4 = blockIdx.x >> 7;
  const int kk = lane >> 2, hh = lane & 3;

  for (int it = 0; it < 4; ++it) {
    const int n = g * 128 + q4 * 16 + w * 4 + it;
    if (lane < 16) {
      int nb = nbrs[n * 16 + lane];
      sNb[w][lane] = nb;
      sMk[w][lane] = mask[n * 16 + lane];
      float dx = pos[nb * 3 + 0] - pos[n * 3 + 0];
      float dy = pos[nb * 3 + 1] - pos[n * 3 + 1];
      float dz = pos[nb * 3 + 2] - pos[n * 3 + 2];
      sD[w][lane] = sqrtf(dx * dx + dy * dy + dz * dz + 1e-12f);
      sRbf[w][lane][50] = 0; sRbf[w][lane][51] = 0;
      *(uint4*)(&sQ[w][lane * 8]) = *(const uint4*)(qext + (size_t)n * 352 + lane * 8);
    }
    if (lane < 50) {
      uint2 u = *(const uint2*)(qext + (size_t)n * 352 + 128 + lane * 4);
      int p = lane * 4;
#pragma unroll
      for (int e = 0; e < 4; ++e) {
        ushort_t bb = ((const ushort_t*)&u)[e];
        int pp = p + e, h2 = pp / 50, r = pp - h2 * 50;
        sQE[w][h2][r] = b2f(bb);
      }
    }
    if (lane < 8) sQE[w][lane >> 1][50 + (lane & 1)] = 0.f;
    {
      int kk2 = lane & 15;
      float dk = sD[w][kk2];
      int r0 = lane >> 4;
#pragma unroll
      for (int j = 0; j < 13; ++j) {
        int r = r0 + j * 4;
        if (r < 50) {
          float t = (dk - (2.f / 49.f) * (float)r) * 24.5f;
          sRbf[w][kk2][r] = f2b(__expf(-0.5f * t * t));
        }
      }
    }
    const int nb = sNb[w][kk];
    const ushort_t* krow = kvb + (size_t)nb * 256 + hh * 32;
    float qk = 0.f;
#pragma unroll
    for (int c8 = 0; c8 < 4; ++c8) {
      uint4 kv4 = *(const uint4*)(krow + c8 * 8);
      const uint_t* q4p = (const uint_t*)(&sQ[w][hh * 32 + c8 * 8]);
      uint_t qa = q4p[0], qb = q4p[1], qc = q4p[2], qd = q4p[3];
      qk += blo(qa) * blo(kv4.x) + bhi(qa) * bhi(kv4.x)
          + blo(qb) * blo(kv4.y) + bhi(qb) * bhi(kv4.y)
          + blo(qc) * blo(kv4.z) + bhi(qc) * bhi(kv4.z)
          + blo(qd) * blo(kv4.w) + bhi(qd) * bhi(kv4.w);
    }
    float qe = 0.f;
#pragma unroll
    for (int c = 0; c < 13; ++c) {
      float4 qv = *(const float4*)(&sQE[w][hh][c * 4]);
      uint2 rv = *(const uint2*)(&sRbf[w][kk][c * 4]);
      qe += qv.x * blo(rv.x) + qv.y * bhi(rv.x)
          + qv.z * blo(rv.y) + qv.w * bhi(rv.y);
    }
    float lg = 0.17677669529663687f * (qk + qe);
    lg = (sMk[w][kk] > 0.f) ? lg : -1e9f;

    float mx = lg;
#pragma unroll
    for (int off = 4; off < 64; off <<= 1) mx = fmaxf(mx, __shfl_xor(mx, off, 64));
    float ex = __expf(lg - mx);
    float sm = ex;
#pragma unroll
    for (int off = 4; off < 64; off <<= 1) sm += __shfl_xor(sm, off, 64);
    sA[w][kk * 4 + hh] = ex / sm * sMk[w][kk];

    if (lane < 50) {
      float r0 = 0.f, r1 = 0.f, r2 = 0.f, r3 = 0.f;
#pragma unroll
      for (int k2 = 0; k2 < 16; ++k2) {
        float rb = b2f(sRbf[w][k2][lane]);
        r0 += sA[w][k2 * 4 + 0] * rb;
        r1 += sA[w][k2 * 4 + 1] * rb;
        r2 += sA[w][k2 * 4 + 2] * rb;
        r3 += sA[w][k2 * 4 + 3] * rb;
      }
      Amsg[(size_t)n * 352 + 128 + 0 * 50 + lane] = f2b(r0);
      Amsg[(size_t)n * 352 + 128 + 1 * 50 + lane] = f2b(r1);
      Amsg[(size_t)n * 352 + 128 + 2 * 50 + lane] = f2b(r2);
      Amsg[(size_t)n * 352 + 128 + 3 * 50 + lane] = f2b(r3);
    }
    {
      const int h2 = lane >> 4;
      float m0v = 0.f, m1v = 0.f;
#pragma unroll
      for (int k2 = 0; k2 < 16; ++k2) {
        int nb2 = sNb[w][k2];
        uint_t vv = *(const uint_t*)(kvb + (size_t)nb2 * 256 + 128 + lane * 2);
        float a = sA[w][k2 * 4 + h2];
        m0v += a * blo(vv);
        m1v += a * bhi(vv);
      }
      uint_t o = (uint_t)f2b(m0v) | ((uint_t)f2b(m1v) << 16);
      *(uint_t*)(&Amsg[(size_t)n * 352 + lane * 2]) = o;
    }
    if (lane < 24) Amsg[(size_t)n * 352 + 328 + lane] = 0;
  }
}

// ---------------------------------------------------------------------------
extern "C" void kernel_launch(void* const* d_in, const int* in_sizes, int n_in,
                              void* d_out, int out_size, void* d_ws, size_t ws_size,
                              hipStream_t stream) {
  const float* enc    = (const float*)d_in[0];
  const float* pos    = (const float*)d_in[1];
  const int*   bidx   = (const int*)  d_in[2];
  const int*   nbrs   = (const int*)  d_in[3];
  const float* mask   = (const float*)d_in[4];
  const float* W_in   = (const float*)d_in[5];
  const float* b_in   = (const float*)d_in[6];
  const float* Wq     = (const float*)d_in[7];
  const float* Wk     = (const float*)d_in[8];
  const float* Wv     = (const float*)d_in[9];
  const float* We     = (const float*)d_in[10];
  const float* Wo     = (const float*)d_in[11];
  const float* bo     = (const float*)d_in[12];
  const float* Wfc    = (const float*)d_in[13];
  const float* bfc    = (const float*)d_in[14];
  const float* ln_g   = (const float*)d_in[15];
  const float* ln_b   = (const float*)d_in[16];
  const float* W_out  = (const float*)d_in[17];
  const float* b_out  = (const float*)d_in[18];
  float* out = (float*)d_out;

  const int N = N_PTS;
  float* ws = (float*)d_ws;
  float*    h      = ws;                                  // N*256 fp32
  ushort_t* qext_b = (ushort_t*)(h + (size_t)N * 256);    // N*352 bf16
  ushort_t* kvb    = qext_b + (size_t)N * 352;            // N*256 bf16
  ushort_t* h_bf   = kvb + (size_t)N * 256;               // N*256 bf16
  ushort_t* Amsg   = h_bf + (size_t)N * 256;              // N*352 bf16
  float*    base   = (float*)(Amsg + (size_t)N * 352);    // 128*256 fp32
  ushort_t* WqkvT  = (ushort_t*)(base + 128 * 256);       // 4*640*256
  ushort_t* BcT    = WqkvT + 4 * 640 * 256;               // 4*256*384
  ushort_t* WfT    = BcT  + 4 * 256 * 384;                // 4*256*256
  ushort_t* WoT    = WfT  + 4 * 256 * 256;                // 128*256

  base_kernel<<<128, 256, 0, stream>>>(enc, W_in, b_in, base);
  embed_kernel<<<N, 256, 0, stream>>>(base, bidx, pos, W_in, h, h_bf);
  prep_qkv<<<(4 * 640 * 256) / 256, 256, 0, stream>>>(Wq, Wk, Wv, We, WqkvT);
  prep_bcat<<<(4 * 256 * 384) / 256, 256, 0, stream>>>(We, Wo, BcT);
  prep_wfc<<<(4 * 256 * 256) / 256, 256, 0, stream>>>(Wfc, WfT);
  prep_wout<<<(128 * 256) / 256, 256, 0, stream>>>(W_out, WoT);

  // layer-0 qkv from embedded features
  fused_layer<2><<<N / 64, 512, 0, stream>>>(
      h_bf, nullptr, nullptr, nullptr, nullptr, nullptr, nullptr, nullptr,
      WqkvT, nullptr, qext_b, kvb, nullptr);

  for (int l = 0; l < NLAYER; ++l) {
    const ushort_t* BcT_l = BcT + (size_t)l * 256 * 384;
    const ushort_t* WfT_l = WfT + (size_t)l * 256 * 256;
    const float* bo_l  = bo  + (size_t)l * 256;
    const float* bfc_l = bfc + (size_t)l * 256;
    const float* lg_l  = ln_g + (size_t)l * 256;
    const float* lb_l  = ln_b + (size_t)l * 256;

    attn_kernel<<<1024, 256, 0, stream>>>(qext_b, kvb, pos, nbrs, mask, Amsg);

    if (l < NLAYER - 1) {
      const ushort_t* Wqkv_next = WqkvT + (size_t)(l + 1) * 640 * 256;
      fused_layer<0><<<N / 64, 512, 0, stream>>>(
          Amsg, BcT_l, bo_l, h, lg_l, lb_l, WfT_l, bfc_l,
          Wqkv_next, nullptr, qext_b, kvb, nullptr);
    } else {
      fused_layer<1><<<N / 64, 512, 0, stream>>>(
          Amsg, BcT_l, bo_l, h, lg_l, lb_l, WfT_l, bfc_l,
          WoT, b_out, nullptr, nullptr, out);
    }
  }
}

// Round 7
// 330.318 us; speedup vs baseline: 1.2386x; 1.0890x over previous
//
#include <hip/hip_runtime.h>
#include <hip/hip_bf16.h>
#include <math.h>

#define N_PTS 16384
#define NLAYER 4

typedef __attribute__((ext_vector_type(8))) short bfrag;
typedef __attribute__((ext_vector_type(4))) float f32x4;
typedef unsigned short ushort_t;
typedef unsigned int uint_t;

__device__ __forceinline__ ushort_t f2b(float f) {
  __hip_bfloat16 h = __float2bfloat16(f);
  return *reinterpret_cast<const ushort_t*>(&h);
}
__device__ __forceinline__ float b2f(ushort_t u) {
  union { uint_t i; float f; } c; c.i = ((uint_t)u) << 16; return c.f;
}
__device__ __forceinline__ float blo(uint_t u) {
  union { uint_t i; float f; } c; c.i = u << 16; return c.f;
}
__device__ __forceinline__ float bhi(uint_t u) {
  union { uint_t i; float f; } c; c.i = u & 0xffff0000u; return c.f;
}

// ---------------------------------------------------------------------------
__global__ __launch_bounds__(256) void base_kernel(
    const float* __restrict__ enc, const float* __restrict__ W_in,
    const float* __restrict__ b_in, float* __restrict__ base)
{
  int b = blockIdx.x, j = threadIdx.x;
  __shared__ float se[256];
  se[j] = enc[b * 256 + j];
  __syncthreads();
  float acc = b_in[j] + W_in[j];
  for (int i = 1; i < 256; ++i) acc += se[i] * W_in[i * 256 + j];
  base[b * 256 + j] = acc;
}

__global__ __launch_bounds__(256) void embed_kernel(
    const float* __restrict__ base, const int* __restrict__ batch_idx,
    const float* __restrict__ pos, const float* __restrict__ W_in,
    float* __restrict__ h, ushort_t* __restrict__ h_bf)
{
  int n = blockIdx.x, j = threadIdx.x;
  int b = batch_idx[n];
  float px = pos[n * 3 + 0], py = pos[n * 3 + 1], pz = pos[n * 3 + 2];
  float v = base[b * 256 + j]
      + px * W_in[256 * 256 + j] + py * W_in[257 * 256 + j] + pz * W_in[258 * 256 + j];
  h[(size_t)n * 256 + j] = v;
  h_bf[(size_t)n * 256 + j] = f2b(v);
}

// ---------------------------------------------------------------------------
// WqkvT[l][j][k], j<128: Wq; 128..327: Wq@We^T; 328..455: Wk; 456..583: Wv; pad 0
__global__ __launch_bounds__(256) void prep_qkv(
    const float* __restrict__ Wq, const float* __restrict__ Wk,
    const float* __restrict__ Wv, const float* __restrict__ We,
    ushort_t* __restrict__ out)
{
  int idx = blockIdx.x * 256 + threadIdx.x;  // < 4*640*256
  int l = idx / (640 * 256);
  int rem = idx - l * (640 * 256);
  int j = rem >> 8, k = rem & 255;
  float v = 0.f;
  if (j < 128) v = Wq[((size_t)l * 256 + k) * 128 + j];
  else if (j < 328) {
    int p = j - 128, hq = p / 50, r = p - hq * 50;
    const float* wq = &Wq[((size_t)l * 256 + k) * 128 + hq * 32];
    const float* we = &We[((size_t)l * 50 + r) * 128 + hq * 32];
#pragma unroll
    for (int d = 0; d < 32; ++d) v += wq[d] * we[d];
  } else if (j < 456) v = Wk[((size_t)l * 256 + k) * 128 + (j - 328)];
  else if (j < 584) v = Wv[((size_t)l * 256 + k) * 128 + (j - 456)];
  out[idx] = f2b(v);
}

// BcT[l][j][k2], ld 384: k2<128: Wo[k2][j]; 128..327: (We@Wo); else 0
__global__ __launch_bounds__(256) void prep_bcat(
    const float* __restrict__ We, const float* __restrict__ Wo, ushort_t* __restrict__ out)
{
  int idx = blockIdx.x * 256 + threadIdx.x;  // < 4*256*384
  int l = idx / (256 * 384);
  int rem = idx - l * (256 * 384);
  int j = rem / 384, k2 = rem - j * 384;
  float v = 0.f;
  if (k2 < 128) v = Wo[((size_t)l * 128 + k2) * 256 + j];
  else if (k2 < 328) {
    int p = k2 - 128, hq = p / 50, r = p - hq * 50;
    const float* we = &We[((size_t)l * 50 + r) * 128 + hq * 32];
    const float* wo = &Wo[((size_t)l * 128 + hq * 32) * 256 + j];
#pragma unroll
    for (int d = 0; d < 32; ++d) v += we[d] * wo[(size_t)d * 256];
  }
  out[idx] = f2b(v);
}

__global__ __launch_bounds__(256) void prep_wfc(
    const float* __restrict__ Wfc, ushort_t* __restrict__ out)
{
  int idx = blockIdx.x * 256 + threadIdx.x;  // < 4*256*256
  int l = idx >> 16, rem = idx & 65535;
  int j = rem >> 8, k = rem & 255;
  out[idx] = f2b(Wfc[((size_t)l * 256 + k) * 256 + j]);
}

__global__ __launch_bounds__(256) void prep_wout(
    const float* __restrict__ W_out, ushort_t* __restrict__ out)
{
  int idx = blockIdx.x * 256 + threadIdx.x;  // < 128*256
  int j = idx >> 8, k = idx & 255;
  out[idx] = (j < 103) ? f2b(W_out[(size_t)k * 103 + j]) : (ushort_t)0;
}

// ---------------------------------------------------------------------------
// Fused layer tail, v2: B operands read DIRECTLY from global (L2-resident
// weights), A/intermediates in XOR-swizzled LDS. 512 blocks x 512 thr,
// 32 rows/block, wave = 32-col strip (GEMM1/2) or 16-col panel slice (GEMM3).
// MODE 0: full layer -> qkv. MODE 1: full layer -> out. MODE 2: qkv only.
template<int MODE>
__global__ __launch_bounds__(512, 4) void fused_layer(
    const ushort_t* __restrict__ A0,    // MODE2: h_bf (ld 256); else Amsg (ld 352)
    const ushort_t* __restrict__ BcT,   // [256][384]
    const float* __restrict__ bo,
    float* __restrict__ h,              // fp32 residual in / gelu out
    const float* __restrict__ lg, const float* __restrict__ lb,
    const ushort_t* __restrict__ WfT,   // [256][256]
    const float* __restrict__ bfc,
    const ushort_t* __restrict__ W3T,   // [640][256] (qkv) or [128][256] (out)
    const float* __restrict__ b3,
    ushort_t* __restrict__ qext_b, ushort_t* __restrict__ kvb,
    float* __restrict__ outF)
{
  __shared__ __align__(16) ushort_t sA[32 * 384];  // GEMM1 A; later sHg (ld 256)
  __shared__ __align__(16) ushort_t sH[32 * 256];  // hln
  __shared__ float pS[8][32], pSS[8][32];

  const int tid = threadIdx.x;
  const int lane = tid & 63, w = tid >> 6;
  const int l15 = lane & 15, l4 = lane >> 4;
  const int m0 = blockIdx.x * 32;
  const int r7 = l15 & 7;                 // row&7 for A-frag rows (both m tiles)

  f32x4 acc[2][2];

  if constexpr (MODE != 2) {
    // ---- stage Amsg tile -> sA [32][384], 16B-chunk XOR swizzle, zero pad
    for (int i = tid; i < 32 * 48; i += 512) {
      int r = i / 48, c8 = i - r * 48;
      uint4 v = (uint4){0, 0, 0, 0};
      if (c8 < 44) v = *(const uint4*)(A0 + (size_t)(m0 + r) * 352 + c8 * 8);
      *(uint4*)(&sA[r * 384 + ((c8 ^ (r & 7)) << 3)]) = v;
    }
    __syncthreads();

    // ---- GEMM1: acc = Amsg @ BcT^T  (K=352, B direct from global)
#pragma unroll
    for (int m = 0; m < 2; ++m) {
      acc[m][0] = (f32x4){0.f, 0.f, 0.f, 0.f};
      acc[m][1] = (f32x4){0.f, 0.f, 0.f, 0.f};
    }
    {
      const ushort_t* bB0 = BcT + (size_t)(w * 32 + l15) * 384 + l4 * 8;
      const ushort_t* bB1 = bB0 + 16 * 384;
#pragma unroll
      for (int k0 = 0; k0 < 352; k0 += 32) {
        const int ch = (k0 >> 3) + l4;
        bfrag a0 = *(const bfrag*)(sA + (0 * 16 + l15) * 384 + ((ch ^ r7) << 3));
        bfrag a1 = *(const bfrag*)(sA + (1 * 16 + l15) * 384 + ((ch ^ r7) << 3));
        bfrag b0 = *(const bfrag*)(bB0 + k0);
        bfrag b1 = *(const bfrag*)(bB1 + k0);
        acc[0][0] = __builtin_amdgcn_mfma_f32_16x16x32_bf16(a0, b0, acc[0][0], 0, 0, 0);
        acc[0][1] = __builtin_amdgcn_mfma_f32_16x16x32_bf16(a0, b1, acc[0][1], 0, 0, 0);
        acc[1][0] = __builtin_amdgcn_mfma_f32_16x16x32_bf16(a1, b0, acc[1][0], 0, 0, 0);
        acc[1][1] = __builtin_amdgcn_mfma_f32_16x16x32_bf16(a1, b1, acc[1][1], 0, 0, 0);
      }
    }

    // ---- epilogue 1: + bo + resid(h), partial row-sums
    const int c0 = w * 32 + l15, c1 = c0 + 16;
    {
      const float bo0 = bo[c0], bo1 = bo[c1];
#pragma unroll
      for (int m = 0; m < 2; ++m)
#pragma unroll
        for (int i = 0; i < 4; ++i) {
          const int rl = m * 16 + l4 * 4 + i;
          const size_t r = (size_t)(m0 + rl);
          float x0 = acc[m][0][i] + bo0 + h[r * 256 + c0];
          float x1 = acc[m][1][i] + bo1 + h[r * 256 + c1];
          acc[m][0][i] = x0; acc[m][1][i] = x1;
          float s = x0 + x1, ss = x0 * x0 + x1 * x1;
          s += __shfl_xor(s, 1, 64); ss += __shfl_xor(ss, 1, 64);
          s += __shfl_xor(s, 2, 64); ss += __shfl_xor(ss, 2, 64);
          s += __shfl_xor(s, 4, 64); ss += __shfl_xor(ss, 4, 64);
          s += __shfl_xor(s, 8, 64); ss += __shfl_xor(ss, 8, 64);
          if (l15 == 0) { pS[w][rl] = s; pSS[w][rl] = ss; }
        }
    }
    __syncthreads();
    // ---- LN -> sH (swizzled)
    {
      const float g0 = lg[c0], g1 = lg[c1];
      const float b0 = lb[c0], b1 = lb[c1];
      const int ch0 = c0 >> 3, ch1 = c1 >> 3;
#pragma unroll
      for (int m = 0; m < 2; ++m)
#pragma unroll
        for (int i = 0; i < 4; ++i) {
          const int rl = m * 16 + l4 * 4 + i;
          float s = 0.f, ss = 0.f;
#pragma unroll
          for (int w2 = 0; w2 < 8; ++w2) { s += pS[w2][rl]; ss += pSS[w2][rl]; }
          float mu = s * (1.f / 256.f);
          float var = ss * (1.f / 256.f) - mu * mu;
          float inv = 1.0f / sqrtf(var + 1e-5f);
          sH[rl * 256 + (((ch0 ^ (rl & 7)) << 3) | (c0 & 7))] =
              f2b(g0 * (acc[m][0][i] - mu) * inv + b0);
          sH[rl * 256 + (((ch1 ^ (rl & 7)) << 3) | (c1 & 7))] =
              f2b(g1 * (acc[m][1][i] - mu) * inv + b1);
        }
    }
    __syncthreads();

    // ---- GEMM2: acc = hln @ WfT^T (K=256, B direct)
#pragma unroll
    for (int m = 0; m < 2; ++m) {
      acc[m][0] = (f32x4){0.f, 0.f, 0.f, 0.f};
      acc[m][1] = (f32x4){0.f, 0.f, 0.f, 0.f};
    }
    {
      const ushort_t* bB0 = WfT + (size_t)(w * 32 + l15) * 256 + l4 * 8;
      const ushort_t* bB1 = bB0 + 16 * 256;
#pragma unroll
      for (int k0 = 0; k0 < 256; k0 += 32) {
        const int ch = (k0 >> 3) + l4;
        bfrag a0 = *(const bfrag*)(sH + (0 * 16 + l15) * 256 + ((ch ^ r7) << 3));
        bfrag a1 = *(const bfrag*)(sH + (1 * 16 + l15) * 256 + ((ch ^ r7) << 3));
        bfrag b0 = *(const bfrag*)(bB0 + k0);
        bfrag b1 = *(const bfrag*)(bB1 + k0);
        acc[0][0] = __builtin_amdgcn_mfma_f32_16x16x32_bf16(a0, b0, acc[0][0], 0, 0, 0);
        acc[0][1] = __builtin_amdgcn_mfma_f32_16x16x32_bf16(a0, b1, acc[0][1], 0, 0, 0);
        acc[1][0] = __builtin_amdgcn_mfma_f32_16x16x32_bf16(a1, b0, acc[1][0], 0, 0, 0);
        acc[1][1] = __builtin_amdgcn_mfma_f32_16x16x32_bf16(a1, b1, acc[1][1], 0, 0, 0);
      }
    }

    // ---- epilogue 2: gelu -> h fp32 + sHg (sA buffer, ld 256, swizzled)
    {
      const float bf0 = bfc[c0], bf1 = bfc[c1];
      const int ch0 = c0 >> 3, ch1 = c1 >> 3;
#pragma unroll
      for (int m = 0; m < 2; ++m)
#pragma unroll
        for (int i = 0; i < 4; ++i) {
          const int rl = m * 16 + l4 * 4 + i;
          const size_t r = (size_t)(m0 + rl);
          float x0 = acc[m][0][i] + bf0;
          float x1 = acc[m][1][i] + bf1;
          float t0 = tanhf(0.7978845608028654f * (x0 + 0.044715f * x0 * x0 * x0));
          float t1 = tanhf(0.7978845608028654f * (x1 + 0.044715f * x1 * x1 * x1));
          float gl0 = 0.5f * x0 * (1.f + t0);
          float gl1 = 0.5f * x1 * (1.f + t1);
          h[r * 256 + c0] = gl0;
          h[r * 256 + c1] = gl1;
          sA[rl * 256 + (((ch0 ^ (rl & 7)) << 3) | (c0 & 7))] = f2b(gl0);
          sA[rl * 256 + (((ch1 ^ (rl & 7)) << 3) | (c1 & 7))] = f2b(gl1);
        }
    }
    __syncthreads();
  } else {
    // MODE 2: stage h_bf tile -> sHg (sA, ld 256, swizzled)
    for (int i = tid; i < 32 * 32; i += 512) {
      int r = i >> 5, c8 = i & 31;
      *(uint4*)(&sA[r * 256 + ((c8 ^ (r & 7)) << 3)]) =
          *(const uint4*)(A0 + (size_t)(m0 + r) * 256 + c8 * 8);
    }
    __syncthreads();
  }

  // ---- GEMM3: g @ W3T^T, 128-col panels, B direct; wave owns 16 cols/panel
  const int NB = (MODE == 1) ? 1 : 5;
  for (int nb = 0; nb < NB; ++nb) {
    f32x4 a3[2];
    a3[0] = (f32x4){0.f, 0.f, 0.f, 0.f};
    a3[1] = (f32x4){0.f, 0.f, 0.f, 0.f};
    const ushort_t* bB = W3T + (size_t)(nb * 128 + w * 16 + l15) * 256 + l4 * 8;
#pragma unroll
    for (int k0 = 0; k0 < 256; k0 += 32) {
      const int ch = (k0 >> 3) + l4;
      bfrag a0 = *(const bfrag*)(sA + (0 * 16 + l15) * 256 + ((ch ^ r7) << 3));
      bfrag a1 = *(const bfrag*)(sA + (1 * 16 + l15) * 256 + ((ch ^ r7) << 3));
      bfrag b0 = *(const bfrag*)(bB + k0);
      a3[0] = __builtin_amdgcn_mfma_f32_16x16x32_bf16(a0, b0, a3[0], 0, 0, 0);
      a3[1] = __builtin_amdgcn_mfma_f32_16x16x32_bf16(a1, b0, a3[1], 0, 0, 0);
    }
    const int c = nb * 128 + w * 16 + l15;
#pragma unroll
    for (int m = 0; m < 2; ++m)
#pragma unroll
      for (int i = 0; i < 4; ++i) {
        const size_t r = (size_t)(m0 + m * 16 + l4 * 4 + i);
        float v = a3[m][i];
        if constexpr (MODE == 1) {
          if (c < 103) outF[r * 103 + c] = v + b3[c];
        } else {
          if (c < 328) qext_b[r * 352 + c] = f2b(v);
          else if (c < 584) kvb[r * 256 + (c - 328)] = f2b(v);
        }
      }
  }
}

// ---------------------------------------------------------------------------
// Attention: K/V straight from L2/L3, all LDS per-wave, no block barriers.
// 1024 blocks x 256 threads; wave handles 4 points.
__global__ __launch_bounds__(256) void attn_kernel(
    const ushort_t* __restrict__ qext, const ushort_t* __restrict__ kvb,
    const float* __restrict__ pos, const int* __restrict__ nbrs,
    const float* __restrict__ mask, ushort_t* __restrict__ Amsg)
{
  __shared__ __align__(16) ushort_t sQ[4][128];
  __shared__ __align__(16) float    sQE[4][4][52];
  __shared__ __align__(16) ushort_t sRbf[4][16][52];
  __shared__ float sA[4][64];
  __shared__ float sD[4][16];
  __shared__ float sMk[4][16];
  __shared__ int   sNb[4][16];

  const int tid = threadIdx.x;
  const int lane = tid & 63, w = tid >> 6;
  const int g = blockIdx.x & 127, q4 = blockIdx.x >> 7;
  const int kk = lane >> 2, hh = lane & 3;

  for (int it = 0; it < 4; ++it) {
    const int n = g * 128 + q4 * 16 + w * 4 + it;
    if (lane < 16) {
      int nb = nbrs[n * 16 + lane];
      sNb[w][lane] = nb;
      sMk[w][lane] = mask[n * 16 + lane];
      float dx = pos[nb * 3 + 0] - pos[n * 3 + 0];
      float dy = pos[nb * 3 + 1] - pos[n * 3 + 1];
      float dz = pos[nb * 3 + 2] - pos[n * 3 + 2];
      sD[w][lane] = sqrtf(dx * dx + dy * dy + dz * dz + 1e-12f);
      sRbf[w][lane][50] = 0; sRbf[w][lane][51] = 0;
      *(uint4*)(&sQ[w][lane * 8]) = *(const uint4*)(qext + (size_t)n * 352 + lane * 8);
    }
    if (lane < 50) {
      uint2 u = *(const uint2*)(qext + (size_t)n * 352 + 128 + lane * 4);
      int p = lane * 4;
#pragma unroll
      for (int e = 0; e < 4; ++e) {
        ushort_t bb = ((const ushort_t*)&u)[e];
        int pp = p + e, h2 = pp / 50, r = pp - h2 * 50;
        sQE[w][h2][r] = b2f(bb);
      }
    }
    if (lane < 8) sQE[w][lane >> 1][50 + (lane & 1)] = 0.f;
    {
      int kk2 = lane & 15;
      float dk = sD[w][kk2];
      int r0 = lane >> 4;
#pragma unroll
      for (int j = 0; j < 13; ++j) {
        int r = r0 + j * 4;
        if (r < 50) {
          float t = (dk - (2.f / 49.f) * (float)r) * 24.5f;
          sRbf[w][kk2][r] = f2b(__expf(-0.5f * t * t));
        }
      }
    }
    const int nb = sNb[w][kk];
    const ushort_t* krow = kvb + (size_t)nb * 256 + hh * 32;
    float qk = 0.f;
#pragma unroll
    for (int c8 = 0; c8 < 4; ++c8) {
      uint4 kv4 = *(const uint4*)(krow + c8 * 8);
      const uint_t* q4p = (const uint_t*)(&sQ[w][hh * 32 + c8 * 8]);
      uint_t qa = q4p[0], qb = q4p[1], qc = q4p[2], qd = q4p[3];
      qk += blo(qa) * blo(kv4.x) + bhi(qa) * bhi(kv4.x)
          + blo(qb) * blo(kv4.y) + bhi(qb) * bhi(kv4.y)
          + blo(qc) * blo(kv4.z) + bhi(qc) * bhi(kv4.z)
          + blo(qd) * blo(kv4.w) + bhi(qd) * bhi(kv4.w);
    }
    float qe = 0.f;
#pragma unroll
    for (int c = 0; c < 13; ++c) {
      float4 qv = *(const float4*)(&sQE[w][hh][c * 4]);
      uint2 rv = *(const uint2*)(&sRbf[w][kk][c * 4]);
      qe += qv.x * blo(rv.x) + qv.y * bhi(rv.x)
          + qv.z * blo(rv.y) + qv.w * bhi(rv.y);
    }
    float lg = 0.17677669529663687f * (qk + qe);
    lg = (sMk[w][kk] > 0.f) ? lg : -1e9f;

    float mx = lg;
#pragma unroll
    for (int off = 4; off < 64; off <<= 1) mx = fmaxf(mx, __shfl_xor(mx, off, 64));
    float ex = __expf(lg - mx);
    float sm = ex;
#pragma unroll
    for (int off = 4; off < 64; off <<= 1) sm += __shfl_xor(sm, off, 64);
    sA[w][kk * 4 + hh] = ex / sm * sMk[w][kk];

    if (lane < 50) {
      float r0 = 0.f, r1 = 0.f, r2 = 0.f, r3 = 0.f;
#pragma unroll
      for (int k2 = 0; k2 < 16; ++k2) {
        float rb = b2f(sRbf[w][k2][lane]);
        r0 += sA[w][k2 * 4 + 0] * rb;
        r1 += sA[w][k2 * 4 + 1] * rb;
        r2 += sA[w][k2 * 4 + 2] * rb;
        r3 += sA[w][k2 * 4 + 3] * rb;
      }
      Amsg[(size_t)n * 352 + 128 + 0 * 50 + lane] = f2b(r0);
      Amsg[(size_t)n * 352 + 128 + 1 * 50 + lane] = f2b(r1);
      Amsg[(size_t)n * 352 + 128 + 2 * 50 + lane] = f2b(r2);
      Amsg[(size_t)n * 352 + 128 + 3 * 50 + lane] = f2b(r3);
    }
    {
      const int h2 = lane >> 4;
      float m0v = 0.f, m1v = 0.f;
#pragma unroll
      for (int k2 = 0; k2 < 16; ++k2) {
        int nb2 = sNb[w][k2];
        uint_t vv = *(const uint_t*)(kvb + (size_t)nb2 * 256 + 128 + lane * 2);
        float a = sA[w][k2 * 4 + h2];
        m0v += a * blo(vv);
        m1v += a * bhi(vv);
      }
      uint_t o = (uint_t)f2b(m0v) | ((uint_t)f2b(m1v) << 16);
      *(uint_t*)(&Amsg[(size_t)n * 352 + lane * 2]) = o;
    }
    if (lane < 24) Amsg[(size_t)n * 352 + 328 + lane] = 0;
  }
}

// ---------------------------------------------------------------------------
extern "C" void kernel_launch(void* const* d_in, const int* in_sizes, int n_in,
                              void* d_out, int out_size, void* d_ws, size_t ws_size,
                              hipStream_t stream) {
  const float* enc    = (const float*)d_in[0];
  const float* pos    = (const float*)d_in[1];
  const int*   bidx   = (const int*)  d_in[2];
  const int*   nbrs   = (const int*)  d_in[3];
  const float* mask   = (const float*)d_in[4];
  const float* W_in   = (const float*)d_in[5];
  const float* b_in   = (const float*)d_in[6];
  const float* Wq     = (const float*)d_in[7];
  const float* Wk     = (const float*)d_in[8];
  const float* Wv     = (const float*)d_in[9];
  const float* We     = (const float*)d_in[10];
  const float* Wo     = (const float*)d_in[11];
  const float* bo     = (const float*)d_in[12];
  const float* Wfc    = (const float*)d_in[13];
  const float* bfc    = (const float*)d_in[14];
  const float* ln_g   = (const float*)d_in[15];
  const float* ln_b   = (const float*)d_in[16];
  const float* W_out  = (const float*)d_in[17];
  const float* b_out  = (const float*)d_in[18];
  float* out = (float*)d_out;

  const int N = N_PTS;
  float* ws = (float*)d_ws;
  float*    h      = ws;                                  // N*256 fp32
  ushort_t* qext_b = (ushort_t*)(h + (size_t)N * 256);    // N*352 bf16
  ushort_t* kvb    = qext_b + (size_t)N * 352;            // N*256 bf16
  ushort_t* h_bf   = kvb + (size_t)N * 256;               // N*256 bf16
  ushort_t* Amsg   = h_bf + (size_t)N * 256;              // N*352 bf16
  float*    base   = (float*)(Amsg + (size_t)N * 352);    // 128*256 fp32
  ushort_t* WqkvT  = (ushort_t*)(base + 128 * 256);       // 4*640*256
  ushort_t* BcT    = WqkvT + 4 * 640 * 256;               // 4*256*384
  ushort_t* WfT    = BcT  + 4 * 256 * 384;                // 4*256*256
  ushort_t* WoT    = WfT  + 4 * 256 * 256;                // 128*256

  base_kernel<<<128, 256, 0, stream>>>(enc, W_in, b_in, base);
  embed_kernel<<<N, 256, 0, stream>>>(base, bidx, pos, W_in, h, h_bf);
  prep_qkv<<<(4 * 640 * 256) / 256, 256, 0, stream>>>(Wq, Wk, Wv, We, WqkvT);
  prep_bcat<<<(4 * 256 * 384) / 256, 256, 0, stream>>>(We, Wo, BcT);
  prep_wfc<<<(4 * 256 * 256) / 256, 256, 0, stream>>>(Wfc, WfT);
  prep_wout<<<(128 * 256) / 256, 256, 0, stream>>>(W_out, WoT);

  // layer-0 qkv from embedded features
  fused_layer<2><<<N / 32, 512, 0, stream>>>(
      h_bf, nullptr, nullptr, nullptr, nullptr, nullptr, nullptr, nullptr,
      WqkvT, nullptr, qext_b, kvb, nullptr);

  for (int l = 0; l < NLAYER; ++l) {
    const ushort_t* BcT_l = BcT + (size_t)l * 256 * 384;
    const ushort_t* WfT_l = WfT + (size_t)l * 256 * 256;
    const float* bo_l  = bo  + (size_t)l * 256;
    const float* bfc_l = bfc + (size_t)l * 256;
    const float* lg_l  = ln_g + (size_t)l * 256;
    const float* lb_l  = ln_b + (size_t)l * 256;

    attn_kernel<<<1024, 256, 0, stream>>>(qext_b, kvb, pos, nbrs, mask, Amsg);

    if (l < NLAYER - 1) {
      const ushort_t* Wqkv_next = WqkvT + (size_t)(l + 1) * 640 * 256;
      fused_layer<0><<<N / 32, 512, 0, stream>>>(
          Amsg, BcT_l, bo_l, h, lg_l, lb_l, WfT_l, bfc_l,
          Wqkv_next, nullptr, qext_b, kvb, nullptr);
    } else {
      fused_layer<1><<<N / 32, 512, 0, stream>>>(
          Amsg, BcT_l, bo_l, h, lg_l, lb_l, WfT_l, bfc_l,
          WoT, b_out, nullptr, nullptr, out);
    }
  }
}